// Round 2
// 763.013 us; speedup vs baseline: 1.0144x; 1.0144x over previous
//
#include <hip/hip_runtime.h>
#include <float.h>

// Problem constants
#define B   32
#define TE  1024
#define TD  64
#define DE  512
#define DD  512
#define U   512
#define K   512   // == DE == DD
#define NB  8     // blocks per batch (256-block coop launch: proven geometry)
#define RPB 128   // t-rows per block

#if __has_builtin(__builtin_amdgcn_exp2f)
#define EXP2F __builtin_amdgcn_exp2f
#else
#define EXP2F exp2f
#endif
#if __has_builtin(__builtin_amdgcn_rcpf)
#define RCPF __builtin_amdgcn_rcpf
#else
#define RCPF(x) (1.0f / (x))
#endif

typedef __attribute__((ext_vector_type(8))) short bf16x8;  // 8 bf16 = 4 VGPRs
typedef __attribute__((ext_vector_type(4))) float f32x4;

__device__ __forceinline__ float tanh_fast(float x) {
    float e = EXP2F(x * 2.8853900817779268f);   // e^{2x}
    return 1.0f - 2.0f * RCPF(e + 1.0f);        // saturates correctly at +-inf
}

__device__ __forceinline__ float wave_reduce_sum(float v) {
    #pragma unroll
    for (int o = 32; o; o >>= 1) v += __shfl_xor(v, o, 64);
    return v;
}

// f32 -> bf16 RNE
__device__ __forceinline__ unsigned short f2bf(float f) {
    unsigned u = __float_as_uint(f);
    unsigned r = (u + 0x7fffu + ((u >> 16) & 1u)) >> 16;
    return (unsigned short)r;
}
__device__ __forceinline__ float bflo(unsigned x) { return __uint_as_float(x << 16); }
__device__ __forceinline__ float bfhi(unsigned x) { return __uint_as_float(x & 0xffff0000u); }
__device__ __forceinline__ void unpack8(uint4 q, float* f) {
    f[0] = bflo(q.x); f[1] = bfhi(q.x); f[2] = bflo(q.y); f[3] = bfhi(q.y);
    f[4] = bflo(q.z); f[5] = bfhi(q.z); f[6] = bflo(q.w); f[7] = bfhi(q.w);
}

// relaxed agent-scope (IC-level) accessors: per-instruction cache bypass,
// no wbl2/inv cache maintenance.
__device__ __forceinline__ float ld_agent(const float* p) {
    return __hip_atomic_load(p, __ATOMIC_RELAXED, __HIP_MEMORY_SCOPE_AGENT);
}
__device__ __forceinline__ void st_agent(float* p, float v) {
    __hip_atomic_store(p, v, __ATOMIC_RELAXED, __HIP_MEMORY_SCOPE_AGENT);
}
__device__ __forceinline__ unsigned long long ld_agent64(const unsigned long long* p) {
    return __hip_atomic_load(p, __ATOMIC_RELAXED, __HIP_MEMORY_SCOPE_AGENT);
}
__device__ __forceinline__ void st_agent64(unsigned long long* p, unsigned long long v) {
    __hip_atomic_store(p, v, __ATOMIC_RELAXED, __HIP_MEMORY_SCOPE_AGENT);
}

// ---------------------------------------------------------------------------
// Fused prep: en cast [0,16384) | de cast [16384,17408) | pass [17408,18432)
// | W transposes [18432,18560) | stats init [18560,18562). One launch.
__global__ __launch_bounds__(256) void k_prep(
        const float4* __restrict__ en_seq, ushort4* __restrict__ en_bf,
        const float4* __restrict__ de_seq, ushort4* __restrict__ de_bf,
        float4* __restrict__ outp,
        const float* __restrict__ W_h, unsigned short* __restrict__ Wh_t,
        const float* __restrict__ W_s, unsigned short* __restrict__ Ws_t,
        unsigned long long* __restrict__ stats)
{
    __shared__ float t[64][65];
    const int blk = blockIdx.x;
    const int tid = threadIdx.x;
    if (blk < 16384) {                       // en_seq f32 -> bf16
        size_t i = (size_t)blk * 256 + tid;
        float4 f = en_seq[i];
        ushort4 r; r.x = f2bf(f.x); r.y = f2bf(f.y); r.z = f2bf(f.z); r.w = f2bf(f.w);
        en_bf[i] = r;
    } else if (blk < 17408) {                // de_seq f32 -> bf16
        size_t i = (size_t)(blk - 16384) * 256 + tid;
        float4 f = de_seq[i];
        ushort4 r; r.x = f2bf(f.x); r.y = f2bf(f.y); r.z = f2bf(f.z); r.w = f2bf(f.w);
        de_bf[i] = r;
    } else if (blk < 18432) {                // de_seq passthrough -> out[:,:,0:DD]
        size_t i = (size_t)(blk - 17408) * 256 + tid;
        size_t r = i >> 7, c = i & 127;
        outp[r * 256 + c] = de_seq[i];
    } else if (blk < 18560) {                // W transpose+cast: Wt[n][k]=W[k][n]
        int id = blk - 18432;
        const float* W = (id < 64) ? W_h : W_s;
        unsigned short* Wt = (id < 64) ? Wh_t : Ws_t;
        int bid = id & 63;
        const int bx = bid & 7, by = bid >> 3;
        const int lx = tid & 63, ly = tid >> 6;
        #pragma unroll
        for (int i = 0; i < 64; i += 4)
            t[ly + i][lx] = W[(size_t)(by * 64 + ly + i) * 512 + bx * 64 + lx];
        __syncthreads();
        #pragma unroll
        for (int i = 0; i < 64; i += 4)
            Wt[(size_t)(bx * 64 + ly + i) * 512 + by * 64 + lx] = f2bf(t[lx][ly + i]);
    } else {                                 // stats init (512 u64)
        int i = (blk - 18560) * 256 + tid;
        stats[i] = 0ull;
    }
}

// ---------------------------------------------------------------------------
// Unified MFMA GEMM: C_bf16[M,512] = A_bf16[M,512] @ Wt_bf16[n][k]^T.
// grid (4, 272): y<256 -> enc (M=32768), y>=256 -> dec (M=2048).
// 128x128 block tile, 4 waves a 64x64, frags direct from global.
__global__ __launch_bounds__(256) void k_mfma(
        const unsigned short* __restrict__ Ae, const unsigned short* __restrict__ Be,
        unsigned short* __restrict__ Ce,
        const unsigned short* __restrict__ Ad, const unsigned short* __restrict__ Bd,
        unsigned short* __restrict__ Cd)
{
    const int tid = threadIdx.x;
    const int w = tid >> 6, lane = tid & 63;
    const int quad = lane >> 4, l16 = lane & 15;
    const short* A; const short* Bt; unsigned short* C; int mb;
    if (blockIdx.y < 256) {
        A = (const short*)Ae; Bt = (const short*)Be; C = Ce; mb = blockIdx.y * 128;
    } else {
        A = (const short*)Ad; Bt = (const short*)Bd; C = Cd; mb = (blockIdx.y - 256) * 128;
    }
    const int m0 = mb + (w >> 1) * 64;
    const int n0 = blockIdx.x * 128 + (w & 1) * 64;

    const short* Ab = A  + (size_t)(m0 + l16) * K + quad * 8;
    const short* Bb = Bt + (size_t)(n0 + l16) * K + quad * 8;

    f32x4 acc[4][4] = {};
    for (int ks = 0; ks < K; ks += 32) {
        bf16x8 af[4], bg[4];
        #pragma unroll
        for (int i = 0; i < 4; i++)
            af[i] = *(const bf16x8*)(Ab + (size_t)i * 16 * K + ks);
        #pragma unroll
        for (int j = 0; j < 4; j++)
            bg[j] = *(const bf16x8*)(Bb + (size_t)j * 16 * K + ks);
        #pragma unroll
        for (int i = 0; i < 4; i++)
            #pragma unroll
            for (int j = 0; j < 4; j++)
                acc[i][j] = __builtin_amdgcn_mfma_f32_16x16x32_bf16(
                    af[i], bg[j], acc[i][j], 0, 0, 0);
    }
    #pragma unroll
    for (int i = 0; i < 4; i++)
        #pragma unroll
        for (int j = 0; j < 4; j++)
            #pragma unroll
            for (int r = 0; r < 4; r++) {
                int m = m0 + i * 16 + quad * 4 + r;
                int n = n0 + j * 16 + l16;
                C[(size_t)m * U + n] = f2bf(acc[i][j][r]);
            }
}

// ---------------------------------------------------------------------------
// Persistent scan: 256 blocks x 1024 threads, cooperative (proven geometry,
// identical workspace to the 762us round-0 kernel).
// OVERLAP RESTRUCTURE vs round 0:
//  * phase1 lane-0 stores UNNORMALIZED p_r = exp2(mu*L2E) into s_p (masked
//    rows stay 0 -> alpha exactly 0). s_mu/s_alpha removed.
//  * phase6 FMA work (unnormalized partial ctx) moved BETWEEN publish and
//    poll: it only needs s_p (post-B1) + step-invariant en_bf registers, so
//    it hides the tag round-trip. Only the 2 pctx stores remain after the
//    poll (poll(s) proves remote blocks finished their cred-reads(s-1) of
//    the buffer being overwritten -- same visibility protocol as round 0).
//  * en_bf phase6 loads are step-invariant -> hoisted once into enreg[32]
//    (static unrolled indexing; LDS-bound occupancy so VGPRs are free).
//  * inv applied at the ctx reduce one step later via inv_prev register.
// Step schedule: phase1 -> B1 -> publish -> phase6-compute -> poll ->
//   phase6-store + cred loads + phase5 -> B3 -> ctx(s-1) reduce * inv_prev.
__global__ __launch_bounds__(1024, 4) void k_scan(
        const unsigned short* __restrict__ enc_bf,
        const unsigned short* __restrict__ dec_bf,
        const unsigned short* __restrict__ en_bf,
        const float* __restrict__ w_c,
        const float* __restrict__ v,
        const int* __restrict__ mask,
        unsigned long long* __restrict__ stats,  // [2][B][NB]
        float* __restrict__ pctx,                // [2][B][NB*4][512]
        float* __restrict__ out)
{
    const int blk = blockIdx.x;
    const int b = blk & 31, g = blk >> 5;    // XCD-local batch grouping
    const int tid = threadIdx.x;
    const int w = tid >> 6, lane = tid & 63;
    const int u = lane * 8;
    const float L2E = 1.4426950408889634f;

    __shared__ __align__(16) unsigned short s_enc[RPB * U];  // 128 KiB
    __shared__ float  s_p[RPB];              // unnormalized exp2(mu*L2E); masked = 0
    __shared__ float  s_cov[RPB];
    __shared__ int    s_active[RPB];
    __shared__ float  s_wsum[16];
    __shared__ float  s_cred[4 * NB][64];    // 8 KiB
    __shared__ int    s_nact;

    const int* maskb = mask + b * TE;
    const unsigned short* encb = enc_bf + ((size_t)b * TE + g * RPB) * U;
    float* alphas = out + (size_t)B * TD * (DD + DE);
    float* covl   = alphas + (size_t)B * TD * TE;

    // lane-resident w_c / v fragments
    float wc[8], vv[8];
    {
        float4 a0 = *(const float4*)&w_c[u];
        float4 a1 = *(const float4*)&w_c[u + 4];
        wc[0]=a0.x; wc[1]=a0.y; wc[2]=a0.z; wc[3]=a0.w;
        wc[4]=a1.x; wc[5]=a1.y; wc[6]=a1.z; wc[7]=a1.w;
        float4 b0 = *(const float4*)&v[u];
        float4 b1 = *(const float4*)&v[u + 4];
        vv[0]=b0.x; vv[1]=b0.y; vv[2]=b0.z; vv[3]=b0.w;
        vv[4]=b1.x; vv[5]=b1.y; vv[6]=b1.z; vv[7]=b1.w;
    }

    // phase6 operands are step-invariant: hoist en_bf quarter-row words once.
    const int e2 = tid & 255, q4 = tid >> 8;   // 256 e-pairs x 4 quarters
    unsigned enreg[32];
    {
        const unsigned* ep = (const unsigned*)
            (en_bf + ((size_t)b * TE + g * RPB + q4 * 32) * DE) + e2;
        #pragma unroll
        for (int r = 0; r < 32; r++) enreg[r] = ep[(size_t)r * (DE / 2)];
    }

    // stage own enc slice into LDS: 131072 B = 8192 uint4, 8 iters
    {
        const uint4* src = (const uint4*)encb;
        uint4* dst = (uint4*)s_enc;
        #pragma unroll
        for (int i = 0; i < 8; i++) dst[i * 1024 + tid] = src[i * 1024 + tid];
    }

    // active-row compaction (waves 0-1, 128 rows), p/cov init
    {
        int act = 0;
        if (tid < RPB) act = (maskb[g * RPB + tid] != 0);
        unsigned long long bal = __ballot(act);
        int pre = __popcll(bal & ((1ull << lane) - 1));
        __shared__ int s_c2[2];
        if (w < 2 && lane == 0) s_c2[w] = __popcll(bal);
        if (tid < RPB) { s_p[tid] = 0.f; s_cov[tid] = 0.f; }
        __syncthreads();
        if (act) {
            int base = (w == 1) ? s_c2[0] : 0;
            s_active[base + pre] = tid;
        }
        if (tid == 0) s_nact = s_c2[0] + s_c2[1];
        __syncthreads();
    }
    const int n_act = s_nact;
    float inv_prev = 0.f;

    for (int s = 0; s < TD; s++) {
        // ---- dec fragment for (b,s)
        float df[8];
        {
            uint4 q = *(const uint4*)(dec_bf + (((size_t)b * TD + s) * U + u));
            unpack8(q, df);
        }

        // ---- phase 1: mu over own active rows (enc from LDS) + local expsum
        float local_esum = 0.f;
        for (int i = w; i < n_act; i += 16) {
            int r = s_active[i];
            float cov = s_cov[r];
            uint4 q = *(const uint4*)(s_enc + (size_t)r * U + u);
            float e[8]; unpack8(q, e);
            float acc = 0.f;
            #pragma unroll
            for (int j = 0; j < 8; j++)
                acc += vv[j] * tanh_fast(fmaf(cov, wc[j], e[j] + df[j]));
            acc = wave_reduce_sum(acc);
            float pe = EXP2F(acc * L2E);
            if (lane == 0) s_p[r] = pe;
            local_esum += pe;
        }
        if (lane == 0) s_wsum[w] = local_esum;

        __syncthreads();   // B1: s_p/s_wsum visible; drains prior-step stores

        // ---- publish (sum_g | tag s+1): wave 0 only
        unsigned long long* sl = stats + ((size_t)(s & 1) * B + b) * NB;
        if (w == 0) {
            float x = (lane < 16) ? s_wsum[lane] : 0.f;
            float sg = wave_reduce_sum(x);
            if (lane == 0) {
                unsigned long long pv =
                    ((unsigned long long)__float_as_uint(sg) << 32) |
                    (unsigned)(s + 1);
                st_agent64(&sl[g], pv);
            }
        }

        // ---- phase 6 COMPUTE (overlaps tag round-trip): pure LDS+FMA,
        //      unnormalized partial ctx over own 32 rows (quarter q4)
        float a0 = 0.f, a1 = 0.f;
        #pragma unroll
        for (int r = 0; r < 32; r++) {
            float p = s_p[q4 * 32 + r];               // broadcast read
            a0 = fmaf(p, bflo(enreg[r]), a0);         // masked: p==0 exact
            a1 = fmaf(p, bfhi(enreg[r]), a1);
        }

        // ---- per-wave poll of all 8 tags -> batch expsum -> inv
        float inv;
        {
            unsigned long long pv = 0;
            for (;;) {
                if (lane < NB) pv = ld_agent64(&sl[lane]);
                unsigned long long okm =
                    __ballot(lane < NB ? ((unsigned)pv == (unsigned)(s + 1)) : 1);
                if (~okm == 0ull) break;
                __builtin_amdgcn_s_sleep(1);
            }
            float tg = (lane < NB) ? __uint_as_float((unsigned)(pv >> 32)) : 0.f;
            tg = wave_reduce_sum(tg);
            inv = RCPF(tg);
        }

        // ---- phase 6 STORE (poll(s) proves remote cred-reads(s-1) of this
        //      buffer are complete -- round-0 protocol)
        {
            float* pw = pctx +
                (((size_t)(s & 1) * B + b) * (NB * 4) + (g * 4 + q4)) * 512;
            st_agent(&pw[2 * e2],     a0);
            st_agent(&pw[2 * e2 + 1], a1);
        }
        // ---- cred loads for ctx(s-1): all threads, 2 floats each
        if (s > 0) {
            int slot = tid >> 5;             // 0..31
            int e = (tid & 31) * 2;          // 0..62
            const float* pp = pctx +
                (((size_t)((s - 1) & 1) * B + b) * (NB * 4) + slot) * 512 + g * 64;
            s_cred[slot][e]     = ld_agent(&pp[e]);
            s_cred[slot][e + 1] = ld_agent(&pp[e + 1]);
        }
        // ---- phase 5: own-row alpha/cov/outputs  [waves 0-1]
        if (tid < RPB) {
            float a = s_p[tid] * inv;        // masked -> exactly 0
            float cov = s_cov[tid];
            size_t rowo = ((size_t)b * TD + s) * TE + g * RPB + tid;
            alphas[rowo] = a;
            covl[rowo]   = fminf(cov, a);
            s_cov[tid] = cov + a;
        }
        __syncthreads();   // B3

        // ---- ctx(s-1) final reduce (apply inv_prev) + store  [threads 0..63]
        if (s > 0 && tid < 64) {
            float ts = 0.f;
            #pragma unroll
            for (int sl2 = 0; sl2 < 4 * NB; sl2++) ts += s_cred[sl2][tid];
            out[((size_t)b * TD + (s - 1)) * (DD + DE) + DD + g * 64 + tid]
                = ts * inv_prev;
        }
        inv_prev = inv;
    }

    // ---- epilogue: one more tag round, then reduce pctx(TD-1)
    __syncthreads();       // orders after ctx(TD-2) reduce; stores already drained at B3
    {
        unsigned long long* sl = stats + ((size_t)(TD & 1) * B + b) * NB;
        if (w == 0 && lane == 0)
            st_agent64(&sl[g], (unsigned long long)(unsigned)(TD + 1));
        unsigned long long pv = 0;
        for (;;) {
            if (lane < NB) pv = ld_agent64(&sl[lane]);
            unsigned long long okm =
                __ballot(lane < NB ? ((unsigned)pv == (unsigned)(TD + 1)) : 1);
            if (~okm == 0ull) break;
            __builtin_amdgcn_s_sleep(1);
        }
    }
    {
        int slot = tid >> 5;
        int e = (tid & 31) * 2;
        const float* pp = pctx +
            (((size_t)((TD - 1) & 1) * B + b) * (NB * 4) + slot) * 512 + g * 64;
        s_cred[slot][e]     = ld_agent(&pp[e]);
        s_cred[slot][e + 1] = ld_agent(&pp[e + 1]);
    }
    __syncthreads();
    if (tid < 64) {
        float ts = 0.f;
        #pragma unroll
        for (int sl2 = 0; sl2 < 4 * NB; sl2++) ts += s_cred[sl2][tid];
        out[((size_t)b * TD + (TD - 1)) * (DD + DE) + DD + g * 64 + tid]
            = ts * inv_prev;
    }
}

// ---------------------------------------------------------------------------
extern "C" void kernel_launch(void* const* d_in, const int* in_sizes, int n_in,
                              void* d_out, int out_size, void* d_ws, size_t ws_size,
                              hipStream_t stream) {
    const float* en_seq = (const float*)d_in[0];
    const float* de_seq = (const float*)d_in[1];
    const int*   mask   = (const int*)d_in[2];
    const float* W_h    = (const float*)d_in[3];
    const float* W_s    = (const float*)d_in[4];
    const float* w_c    = (const float*)d_in[5];
    const float* v      = (const float*)d_in[6];
    float* out = (float*)d_out;

    // workspace layout (~70.5 MiB, identical to round 0). de_bf/Ws_t ALIAS
    // pctx (lifetimes disjoint: dead before k_scan first writes pctx).
    unsigned short* enc_bf = (unsigned short*)d_ws;        // B*TE*U  bf16 = 32 MiB
    unsigned short* en_bf  = enc_bf + (size_t)B * TE * U;  // B*TE*DE bf16 = 32 MiB
    unsigned short* dec_bf = en_bf  + (size_t)B * TE * DE; // B*TD*U  bf16 = 2 MiB
    unsigned short* Wh_t   = dec_bf + (size_t)B * TD * U;  // 512*512 bf16 = 0.5 MiB
    float* pctx = (float*)(Wh_t + (size_t)K * U);          // 2*B*32*512 f32 = 4 MiB
    unsigned short* de_bf  = (unsigned short*)pctx;        // B*TD*DD bf16 = 2 MiB (alias)
    unsigned short* Ws_t   = de_bf + (size_t)B * TD * DD;  // 0.5 MiB (alias)
    unsigned long long* stats =
        (unsigned long long*)(pctx + (size_t)2 * B * 32 * 512);  // 512 u64

    k_prep<<<18562, 256, 0, stream>>>((const float4*)en_seq, (ushort4*)en_bf,
                                      (const float4*)de_seq, (ushort4*)de_bf,
                                      (float4*)out, W_h, Wh_t, W_s, Ws_t, stats);
    k_mfma<<<dim3(4, 272), 256, 0, stream>>>(en_bf, Wh_t, enc_bf,
                                             de_bf, Ws_t, dec_bf);

    void* args[] = { (void*)&enc_bf, (void*)&dec_bf, (void*)&en_bf,
                     (void*)&w_c, (void*)&v, (void*)&mask,
                     (void*)&stats, (void*)&pctx, (void*)&out };
    hipLaunchCooperativeKernel((const void*)k_scan, dim3(256), dim3(1024),
                               args, 0, stream);
}

// Round 3
// 746.207 us; speedup vs baseline: 1.0373x; 1.0225x over previous
//
#include <hip/hip_runtime.h>
#include <float.h>

// Problem constants
#define B   32
#define TE  1024
#define TD  64
#define DE  512
#define DD  512
#define U   512
#define K   512   // == DE == DD
#define NB  8     // blocks per batch (256-block coop launch: proven geometry)
#define RPB 128   // t-rows per block

#if __has_builtin(__builtin_amdgcn_exp2f)
#define EXP2F __builtin_amdgcn_exp2f
#else
#define EXP2F exp2f
#endif
#if __has_builtin(__builtin_amdgcn_rcpf)
#define RCPF __builtin_amdgcn_rcpf
#else
#define RCPF(x) (1.0f / (x))
#endif

typedef __attribute__((ext_vector_type(8))) short bf16x8;  // 8 bf16 = 4 VGPRs
typedef __attribute__((ext_vector_type(4))) float f32x4;

__device__ __forceinline__ float tanh_fast(float x) {
    float e = EXP2F(x * 2.8853900817779268f);   // e^{2x}
    return 1.0f - 2.0f * RCPF(e + 1.0f);        // saturates correctly at +-inf
}

__device__ __forceinline__ float wave_reduce_sum(float v) {
    #pragma unroll
    for (int o = 32; o; o >>= 1) v += __shfl_xor(v, o, 64);
    return v;
}

// f32 -> bf16 RNE
__device__ __forceinline__ unsigned short f2bf(float f) {
    unsigned u = __float_as_uint(f);
    unsigned r = (u + 0x7fffu + ((u >> 16) & 1u)) >> 16;
    return (unsigned short)r;
}
__device__ __forceinline__ float bflo(unsigned x) { return __uint_as_float(x << 16); }
__device__ __forceinline__ float bfhi(unsigned x) { return __uint_as_float(x & 0xffff0000u); }
__device__ __forceinline__ void unpack8(uint4 q, float* f) {
    f[0] = bflo(q.x); f[1] = bfhi(q.x); f[2] = bflo(q.y); f[3] = bfhi(q.y);
    f[4] = bflo(q.z); f[5] = bfhi(q.z); f[6] = bflo(q.w); f[7] = bfhi(q.w);
}

// relaxed agent-scope accessors (tag exchange only)
__device__ __forceinline__ unsigned long long ld_agent64(const unsigned long long* p) {
    return __hip_atomic_load(p, __ATOMIC_RELAXED, __HIP_MEMORY_SCOPE_AGENT);
}
__device__ __forceinline__ void st_agent64(unsigned long long* p, unsigned long long v) {
    __hip_atomic_store(p, v, __ATOMIC_RELAXED, __HIP_MEMORY_SCOPE_AGENT);
}

// ---------------------------------------------------------------------------
// Fused prep: en cast [0,16384) | de cast [16384,17408) | pass [17408,18432)
// | W transposes [18432,18560) | stats init [18560,18562). One launch.
__global__ __launch_bounds__(256) void k_prep(
        const float4* __restrict__ en_seq, ushort4* __restrict__ en_bf,
        const float4* __restrict__ de_seq, ushort4* __restrict__ de_bf,
        float4* __restrict__ outp,
        const float* __restrict__ W_h, unsigned short* __restrict__ Wh_t,
        const float* __restrict__ W_s, unsigned short* __restrict__ Ws_t,
        unsigned long long* __restrict__ stats)
{
    __shared__ float t[64][65];
    const int blk = blockIdx.x;
    const int tid = threadIdx.x;
    if (blk < 16384) {                       // en_seq f32 -> bf16
        size_t i = (size_t)blk * 256 + tid;
        float4 f = en_seq[i];
        ushort4 r; r.x = f2bf(f.x); r.y = f2bf(f.y); r.z = f2bf(f.z); r.w = f2bf(f.w);
        en_bf[i] = r;
    } else if (blk < 17408) {                // de_seq f32 -> bf16
        size_t i = (size_t)(blk - 16384) * 256 + tid;
        float4 f = de_seq[i];
        ushort4 r; r.x = f2bf(f.x); r.y = f2bf(f.y); r.z = f2bf(f.z); r.w = f2bf(f.w);
        de_bf[i] = r;
    } else if (blk < 18432) {                // de_seq passthrough -> out[:,:,0:DD]
        size_t i = (size_t)(blk - 17408) * 256 + tid;
        size_t r = i >> 7, c = i & 127;
        outp[r * 256 + c] = de_seq[i];
    } else if (blk < 18560) {                // W transpose+cast: Wt[n][k]=W[k][n]
        int id = blk - 18432;
        const float* W = (id < 64) ? W_h : W_s;
        unsigned short* Wt = (id < 64) ? Wh_t : Ws_t;
        int bid = id & 63;
        const int bx = bid & 7, by = bid >> 3;
        const int lx = tid & 63, ly = tid >> 6;
        #pragma unroll
        for (int i = 0; i < 64; i += 4)
            t[ly + i][lx] = W[(size_t)(by * 64 + ly + i) * 512 + bx * 64 + lx];
        __syncthreads();
        #pragma unroll
        for (int i = 0; i < 64; i += 4)
            Wt[(size_t)(bx * 64 + ly + i) * 512 + by * 64 + lx] = f2bf(t[lx][ly + i]);
    } else {                                 // stats init (512 u64)
        int i = (blk - 18560) * 256 + tid;
        stats[i] = 0ull;
    }
}

// ---------------------------------------------------------------------------
// Unified MFMA GEMM: C_bf16[M,512] = A_bf16[M,512] @ Wt_bf16[n][k]^T.
// grid (4, 272): y<256 -> enc (M=32768), y>=256 -> dec (M=2048).
__global__ __launch_bounds__(256) void k_mfma(
        const unsigned short* __restrict__ Ae, const unsigned short* __restrict__ Be,
        unsigned short* __restrict__ Ce,
        const unsigned short* __restrict__ Ad, const unsigned short* __restrict__ Bd,
        unsigned short* __restrict__ Cd)
{
    const int tid = threadIdx.x;
    const int w = tid >> 6, lane = tid & 63;
    const int quad = lane >> 4, l16 = lane & 15;
    const short* A; const short* Bt; unsigned short* C; int mb;
    if (blockIdx.y < 256) {
        A = (const short*)Ae; Bt = (const short*)Be; C = Ce; mb = blockIdx.y * 128;
    } else {
        A = (const short*)Ad; Bt = (const short*)Bd; C = Cd; mb = (blockIdx.y - 256) * 128;
    }
    const int m0 = mb + (w >> 1) * 64;
    const int n0 = blockIdx.x * 128 + (w & 1) * 64;

    const short* Ab = A  + (size_t)(m0 + l16) * K + quad * 8;
    const short* Bb = Bt + (size_t)(n0 + l16) * K + quad * 8;

    f32x4 acc[4][4] = {};
    for (int ks = 0; ks < K; ks += 32) {
        bf16x8 af[4], bg[4];
        #pragma unroll
        for (int i = 0; i < 4; i++)
            af[i] = *(const bf16x8*)(Ab + (size_t)i * 16 * K + ks);
        #pragma unroll
        for (int j = 0; j < 4; j++)
            bg[j] = *(const bf16x8*)(Bb + (size_t)j * 16 * K + ks);
        #pragma unroll
        for (int i = 0; i < 4; i++)
            #pragma unroll
            for (int j = 0; j < 4; j++)
                acc[i][j] = __builtin_amdgcn_mfma_f32_16x16x32_bf16(
                    af[i], bg[j], acc[i][j], 0, 0, 0);
    }
    #pragma unroll
    for (int i = 0; i < 4; i++)
        #pragma unroll
        for (int j = 0; j < 4; j++)
            #pragma unroll
            for (int r = 0; r < 4; r++) {
                int m = m0 + i * 16 + quad * 4 + r;
                int n = n0 + j * 16 + l16;
                C[(size_t)m * U + n] = f2bf(acc[i][j][r]);
            }
}

// ---------------------------------------------------------------------------
// Persistent scan v3: 256 blocks x 1024 threads, cooperative.
// KEY RESTRUCTURE: ctx is NOT part of the recurrence (only alpha->cov is).
// All cross-block ctx machinery (pctx agent stores, cred HBM reads, B3 drain,
// epilogue tag round) is removed from the loop. Each block writes its OWN
// normalized 512-float ctx partial per step with plain stores into a private
// slab that ALIASES its (dead after enreg-hoist) en_bf slice; a post-kernel
// k_ctx sums the 8 partials. The scan's only cross-block exchange is the
// 64-bit expsum tag (payload packed with tag -> no ordering requirements).
// Per step: phase1 -> B1(__syncthreads; stale drains only) -> publish ->
// phase6(own partial, hides poll) -> poll -> phase5 + quarter partials to
// LDS -> B2 (raw s_barrier + lgkmcnt(0) ONLY: no vmem drain) -> quarter
// reduce + plain pctx store.
// NOTE: en_bf and pctx alias (same buffer) -> deliberately NOT __restrict__.
__global__ __launch_bounds__(1024, 4) void k_scan(
        const unsigned short* __restrict__ enc_bf,
        const unsigned short* __restrict__ dec_bf,
        const unsigned short* en_bf,     // aliases pctx!
        const float* __restrict__ w_c,
        const float* __restrict__ v,
        const int* __restrict__ mask,
        unsigned long long* __restrict__ stats,  // [2][B][NB]
        float* pctx,                     // aliases en_bf! [B][NB][TD][512]
        float* __restrict__ out)
{
    const int blk = blockIdx.x;
    const int b = blk & 31, g = blk >> 5;    // batch's 8 blocks share an XCD
    const int tid = threadIdx.x;
    const int w = tid >> 6, lane = tid & 63;
    const int u = lane * 8;
    const float L2E = 1.4426950408889634f;

    __shared__ __align__(16) unsigned short s_enc[RPB * U];  // 128 KiB
    __shared__ float  s_p[RPB];              // unnormalized exp2(mu*L2E); masked = 0
    __shared__ float  s_cov[RPB];
    __shared__ int    s_active[RPB];
    __shared__ float  s_wsum[16];
    __shared__ float  s_q[4][512];           // quarter partials, 8 KiB
    __shared__ int    s_nact;

    const int* maskb = mask + b * TE;
    const unsigned short* encb = enc_bf + ((size_t)b * TE + g * RPB) * U;
    float* alphas = out + (size_t)B * TD * (DD + DE);
    float* covl   = alphas + (size_t)B * TD * TE;

    // lane-resident w_c / v fragments
    float wc[8], vv[8];
    {
        float4 a0 = *(const float4*)&w_c[u];
        float4 a1 = *(const float4*)&w_c[u + 4];
        wc[0]=a0.x; wc[1]=a0.y; wc[2]=a0.z; wc[3]=a0.w;
        wc[4]=a1.x; wc[5]=a1.y; wc[6]=a1.z; wc[7]=a1.w;
        float4 b0 = *(const float4*)&v[u];
        float4 b1 = *(const float4*)&v[u + 4];
        vv[0]=b0.x; vv[1]=b0.y; vv[2]=b0.z; vv[3]=b0.w;
        vv[4]=b1.x; vv[5]=b1.y; vv[6]=b1.z; vv[7]=b1.w;
    }

    // phase6 operands are step-invariant: hoist en_bf quarter-row words once.
    // After this hoist the block's en_bf slice is DEAD -> reused as its pctx
    // slab (128 KiB each, exact fit). B1(step 0) orders hoist before any
    // pctx write block-wide.
    const int e2 = tid & 255, q4 = tid >> 8;   // 256 e-pairs x 4 quarters
    unsigned enreg[32];
    {
        const unsigned* ep = (const unsigned*)
            (en_bf + ((size_t)b * TE + g * RPB + q4 * 32) * DE) + e2;
        #pragma unroll
        for (int r = 0; r < 32; r++) enreg[r] = ep[(size_t)r * (DE / 2)];
    }
    // private slab: floats at en_bf slice of this (b,g)
    float* myctx = pctx + ((size_t)b * 1024 + g * RPB) * 256;  // 64*512 f32

    // stage own enc slice into LDS: 131072 B = 8192 uint4, 8 iters
    {
        const uint4* src = (const uint4*)encb;
        uint4* dst = (uint4*)s_enc;
        #pragma unroll
        for (int i = 0; i < 8; i++) dst[i * 1024 + tid] = src[i * 1024 + tid];
    }

    // active-row compaction (waves 0-1, 128 rows), p/cov init
    {
        int act = 0;
        if (tid < RPB) act = (maskb[g * RPB + tid] != 0);
        unsigned long long bal = __ballot(act);
        int pre = __popcll(bal & ((1ull << lane) - 1));
        __shared__ int s_c2[2];
        if (w < 2 && lane == 0) s_c2[w] = __popcll(bal);
        if (tid < RPB) { s_p[tid] = 0.f; s_cov[tid] = 0.f; }
        __syncthreads();
        if (act) {
            int base = (w == 1) ? s_c2[0] : 0;
            s_active[base + pre] = tid;
        }
        if (tid == 0) s_nact = s_c2[0] + s_c2[1];
        __syncthreads();
    }
    const int n_act = s_nact;

    // pipelined dec fragment
    uint4 qd = *(const uint4*)(dec_bf + ((size_t)b * TD) * U + u);

    for (int s = 0; s < TD; s++) {
        float df[8];
        unpack8(qd, df);

        // ---- phase 1: mu over own active rows (enc from LDS) + local expsum
        float local_esum = 0.f;
        for (int i = w; i < n_act; i += 16) {
            int r = s_active[i];
            float cov = s_cov[r];
            uint4 q = *(const uint4*)(s_enc + (size_t)r * U + u);
            float e[8]; unpack8(q, e);
            float acc = 0.f;
            #pragma unroll
            for (int j = 0; j < 8; j++)
                acc += vv[j] * tanh_fast(fmaf(cov, wc[j], e[j] + df[j]));
            acc = wave_reduce_sum(acc);
            float pe = EXP2F(acc * L2E);
            if (lane == 0) s_p[r] = pe;
            local_esum += pe;
        }
        if (lane == 0) s_wsum[w] = local_esum;

        __syncthreads();   // B1: s_p/s_wsum visible (stale vmem drains only)

        // ---- publish (sum_g | tag s+1): wave 0 only
        unsigned long long* sl = stats + ((size_t)(s & 1) * B + b) * NB;
        if (w == 0) {
            float x = (lane < 16) ? s_wsum[lane] : 0.f;
            float sg = wave_reduce_sum(x);
            if (lane == 0) {
                unsigned long long pv =
                    ((unsigned long long)__float_as_uint(sg) << 32) |
                    (unsigned)(s + 1);
                st_agent64(&sl[g], pv);
            }
        }

        // ---- prefetch next dec fragment (latency hides under phase6+poll)
        {
            int sn = (s + 1 < TD) ? s + 1 : s;
            qd = *(const uint4*)(dec_bf + (((size_t)b * TD + sn) * U + u));
        }

        // ---- phase 6 COMPUTE (hides tag round-trip): pure LDS+FMA,
        //      unnormalized partial ctx over own 32 rows (quarter q4)
        float a0 = 0.f, a1 = 0.f;
        #pragma unroll
        for (int r = 0; r < 32; r++) {
            float p = s_p[q4 * 32 + r];               // broadcast read
            a0 = fmaf(p, bflo(enreg[r]), a0);         // masked: p==0 exact
            a1 = fmaf(p, bfhi(enreg[r]), a1);
        }

        // ---- per-wave poll of all 8 tags -> batch expsum -> inv
        float inv;
        {
            unsigned long long pv = 0;
            for (;;) {
                if (lane < NB) pv = ld_agent64(&sl[lane]);
                unsigned long long okm =
                    __ballot(lane < NB ? ((unsigned)pv == (unsigned)(s + 1)) : 1);
                if (~okm == 0ull) break;
                __builtin_amdgcn_s_sleep(1);
            }
            float tg = (lane < NB) ? __uint_as_float((unsigned)(pv >> 32)) : 0.f;
            tg = wave_reduce_sum(tg);
            inv = RCPF(tg);
        }

        // ---- phase 5: own-row alpha/cov/outputs  [waves 0-1]
        if (tid < RPB) {
            float a = s_p[tid] * inv;        // masked -> exactly 0
            float cov = s_cov[tid];
            size_t rowo = ((size_t)b * TD + s) * TE + g * RPB + tid;
            alphas[rowo] = a;
            covl[rowo]   = fminf(cov, a);
            s_cov[tid] = cov + a;
        }
        // ---- quarter partials to LDS
        s_q[q4][2 * e2]     = a0;
        s_q[q4][2 * e2 + 1] = a1;

        // ---- B2: LDS-only barrier (no vmem drain; pctx/alphas stores from
        //      this and earlier steps drain lazily -- no intra-kernel reader)
        asm volatile("s_waitcnt lgkmcnt(0)" ::: "memory");
        __builtin_amdgcn_s_barrier();
        __builtin_amdgcn_sched_barrier(0);

        // ---- quarter reduce + normalized plain store to private slab
        //      (reads s_q between B2(s) and B1(s+1); writes to s_q occur
        //       between B1 and B2 -> barrier-disjoint, single buffer safe)
        if (tid < 512) {
            float ts = s_q[0][tid] + s_q[1][tid] + s_q[2][tid] + s_q[3][tid];
            myctx[(size_t)s * 512 + tid] = ts * inv;
        }
    }
    // no epilogue: pctx read by k_ctx after kernel-boundary flush
}

// ---------------------------------------------------------------------------
// ctx final reduce: out ctx = sum over the 8 per-block partials.
// pctx[b][g] slab at float offset (b*1024+g*128)*256, laid out [s][e].
__global__ __launch_bounds__(1024) void k_ctx(
        const float* __restrict__ pctx, float* __restrict__ out)
{
    int idx = blockIdx.x * 1024 + threadIdx.x;   // 1,048,576 total
    int b = idx >> 15, rem = idx & 32767;        // rem = s*512 + e
    const float* p = pctx + (size_t)b * 262144 + rem;
    float t = 0.f;
    #pragma unroll
    for (int g = 0; g < NB; g++) t += p[(size_t)g * 32768];
    int s = rem >> 9, e = rem & 511;
    out[((size_t)b * TD + s) * (DD + DE) + DD + e] = t;
}

// ---------------------------------------------------------------------------
extern "C" void kernel_launch(void* const* d_in, const int* in_sizes, int n_in,
                              void* d_out, int out_size, void* d_ws, size_t ws_size,
                              hipStream_t stream) {
    const float* en_seq = (const float*)d_in[0];
    const float* de_seq = (const float*)d_in[1];
    const int*   mask   = (const int*)d_in[2];
    const float* W_h    = (const float*)d_in[3];
    const float* W_s    = (const float*)d_in[4];
    const float* w_c    = (const float*)d_in[5];
    const float* v      = (const float*)d_in[6];
    float* out = (float*)d_out;

    // workspace layout (~69 MiB, under the proven 70.5 MiB footprint).
    // en_bf doubles as the per-block ctx-partial slab during k_scan
    // (each block's 128-KiB en slice is dead after its enreg hoist).
    unsigned short* enc_bf = (unsigned short*)d_ws;        // B*TE*U  bf16 = 32 MiB
    unsigned short* en_bf  = enc_bf + (size_t)B * TE * U;  // B*TE*DE bf16 = 32 MiB
    unsigned short* dec_bf = en_bf  + (size_t)B * TE * DE; // B*TD*U  bf16 = 2 MiB
    unsigned short* Wh_t   = dec_bf + (size_t)B * TD * U;  // 512*512 bf16 = 0.5 MiB
    unsigned short* de_bf  = Wh_t   + (size_t)K * U;       // B*TD*DD bf16 = 2 MiB
    unsigned short* Ws_t   = de_bf  + (size_t)B * TD * DD; // 0.5 MiB
    unsigned long long* stats =
        (unsigned long long*)(Ws_t + (size_t)K * U);       // 512 u64
    float* pctx = (float*)en_bf;                           // alias

    k_prep<<<18562, 256, 0, stream>>>((const float4*)en_seq, (ushort4*)en_bf,
                                      (const float4*)de_seq, (ushort4*)de_bf,
                                      (float4*)out, W_h, Wh_t, W_s, Ws_t, stats);
    k_mfma<<<dim3(4, 272), 256, 0, stream>>>(en_bf, Wh_t, enc_bf,
                                             de_bf, Ws_t, dec_bf);

    void* args[] = { (void*)&enc_bf, (void*)&dec_bf, (void*)&en_bf,
                     (void*)&w_c, (void*)&v, (void*)&mask,
                     (void*)&stats, (void*)&pctx, (void*)&out };
    hipLaunchCooperativeKernel((const void*)k_scan, dim3(256), dim3(1024),
                               args, 0, stream);

    k_ctx<<<1024, 1024, 0, stream>>>(pctx, out);
}

// Round 5
// 570.583 us; speedup vs baseline: 1.3566x; 1.3078x over previous
//
#include <hip/hip_runtime.h>
#include <float.h>

// Problem constants
#define B   32
#define TE  1024
#define TD  64
#define DE  512
#define DD  512
#define U   512
#define K   512   // == DE == DD
#define NB  8     // blocks per batch (256-block coop launch: proven geometry)
#define RPB 128   // t-rows per block (slice size for outputs/slab)

#if __has_builtin(__builtin_amdgcn_exp2f)
#define EXP2F __builtin_amdgcn_exp2f
#else
#define EXP2F exp2f
#endif
#if __has_builtin(__builtin_amdgcn_rcpf)
#define RCPF __builtin_amdgcn_rcpf
#else
#define RCPF(x) (1.0f / (x))
#endif

typedef __attribute__((ext_vector_type(8))) short bf16x8;  // 8 bf16 = 4 VGPRs
typedef __attribute__((ext_vector_type(4))) float f32x4;

__device__ __forceinline__ float tanh_fast(float x) {
    float e = EXP2F(x * 2.8853900817779268f);   // e^{2x}
    return 1.0f - 2.0f * RCPF(e + 1.0f);        // saturates correctly at +-inf
}

__device__ __forceinline__ float wave_reduce_sum(float v) {
    #pragma unroll
    for (int o = 32; o; o >>= 1) v += __shfl_xor(v, o, 64);
    return v;
}

// f32 -> bf16 RNE
__device__ __forceinline__ unsigned short f2bf(float f) {
    unsigned u = __float_as_uint(f);
    unsigned r = (u + 0x7fffu + ((u >> 16) & 1u)) >> 16;
    return (unsigned short)r;
}
__device__ __forceinline__ float bflo(unsigned x) { return __uint_as_float(x << 16); }
__device__ __forceinline__ float bfhi(unsigned x) { return __uint_as_float(x & 0xffff0000u); }
__device__ __forceinline__ void unpack8(uint4 q, float* f) {
    f[0] = bflo(q.x); f[1] = bfhi(q.x); f[2] = bflo(q.y); f[3] = bfhi(q.y);
    f[4] = bflo(q.z); f[5] = bfhi(q.z); f[6] = bflo(q.w); f[7] = bfhi(q.w);
}

// relaxed agent-scope accessors (tag exchange only)
__device__ __forceinline__ unsigned long long ld_agent64(const unsigned long long* p) {
    return __hip_atomic_load(p, __ATOMIC_RELAXED, __HIP_MEMORY_SCOPE_AGENT);
}
__device__ __forceinline__ void st_agent64(unsigned long long* p, unsigned long long v) {
    __hip_atomic_store(p, v, __ATOMIC_RELAXED, __HIP_MEMORY_SCOPE_AGENT);
}

// LDS-only barrier: no vmcnt drain (used where no vmem ordering is needed)
#define LBAR() do { \
    asm volatile("s_waitcnt lgkmcnt(0)" ::: "memory"); \
    __builtin_amdgcn_s_barrier(); \
    __builtin_amdgcn_sched_barrier(0); \
} while (0)

// ---------------------------------------------------------------------------
// Fused prep: en cast [0,16384) | de cast [16384,17408) | pass [17408,18432)
// | W transposes [18432,18560) | stats init [18560,18562). One launch.
__global__ __launch_bounds__(256) void k_prep(
        const float4* __restrict__ en_seq, ushort4* __restrict__ en_bf,
        const float4* __restrict__ de_seq, ushort4* __restrict__ de_bf,
        float4* __restrict__ outp,
        const float* __restrict__ W_h, unsigned short* __restrict__ Wh_t,
        const float* __restrict__ W_s, unsigned short* __restrict__ Ws_t,
        unsigned long long* __restrict__ stats)
{
    __shared__ float t[64][65];
    const int blk = blockIdx.x;
    const int tid = threadIdx.x;
    if (blk < 16384) {                       // en_seq f32 -> bf16
        size_t i = (size_t)blk * 256 + tid;
        float4 f = en_seq[i];
        ushort4 r; r.x = f2bf(f.x); r.y = f2bf(f.y); r.z = f2bf(f.z); r.w = f2bf(f.w);
        en_bf[i] = r;
    } else if (blk < 17408) {                // de_seq f32 -> bf16
        size_t i = (size_t)(blk - 16384) * 256 + tid;
        float4 f = de_seq[i];
        ushort4 r; r.x = f2bf(f.x); r.y = f2bf(f.y); r.z = f2bf(f.z); r.w = f2bf(f.w);
        de_bf[i] = r;
    } else if (blk < 18432) {                // de_seq passthrough -> out[:,:,0:DD]
        size_t i = (size_t)(blk - 17408) * 256 + tid;
        size_t r = i >> 7, c = i & 127;
        outp[r * 256 + c] = de_seq[i];
    } else if (blk < 18560) {                // W transpose+cast: Wt[n][k]=W[k][n]
        int id = blk - 18432;
        const float* W = (id < 64) ? W_h : W_s;
        unsigned short* Wt = (id < 64) ? Wh_t : Ws_t;
        int bid = id & 63;
        const int bx = bid & 7, by = bid >> 3;
        const int lx = tid & 63, ly = tid >> 6;
        #pragma unroll
        for (int i = 0; i < 64; i += 4)
            t[ly + i][lx] = W[(size_t)(by * 64 + ly + i) * 512 + bx * 64 + lx];
        __syncthreads();
        #pragma unroll
        for (int i = 0; i < 64; i += 4)
            Wt[(size_t)(bx * 64 + ly + i) * 512 + by * 64 + lx] = f2bf(t[lx][ly + i]);
    } else {                                 // stats init (512 u64)
        int i = (blk - 18560) * 256 + tid;
        stats[i] = 0ull;
    }
}

// ---------------------------------------------------------------------------
// Unified MFMA GEMM: C_bf16[M,512] = A_bf16[M,512] @ Wt_bf16[n][k]^T.
// grid (4, 272): y<256 -> enc (M=32768), y>=256 -> dec (M=2048).
__global__ __launch_bounds__(256) void k_mfma(
        const unsigned short* __restrict__ Ae, const unsigned short* __restrict__ Be,
        unsigned short* __restrict__ Ce,
        const unsigned short* __restrict__ Ad, const unsigned short* __restrict__ Bd,
        unsigned short* __restrict__ Cd)
{
    const int tid = threadIdx.x;
    const int w = tid >> 6, lane = tid & 63;
    const int quad = lane >> 4, l16 = lane & 15;
    const short* A; const short* Bt; unsigned short* C; int mb;
    if (blockIdx.y < 256) {
        A = (const short*)Ae; Bt = (const short*)Be; C = Ce; mb = blockIdx.y * 128;
    } else {
        A = (const short*)Ad; Bt = (const short*)Bd; C = Cd; mb = (blockIdx.y - 256) * 128;
    }
    const int m0 = mb + (w >> 1) * 64;
    const int n0 = blockIdx.x * 128 + (w & 1) * 64;

    const short* Ab = A  + (size_t)(m0 + l16) * K + quad * 8;
    const short* Bb = Bt + (size_t)(n0 + l16) * K + quad * 8;

    f32x4 acc[4][4] = {};
    for (int ks = 0; ks < K; ks += 32) {
        bf16x8 af[4], bg[4];
        #pragma unroll
        for (int i = 0; i < 4; i++)
            af[i] = *(const bf16x8*)(Ab + (size_t)i * 16 * K + ks);
        #pragma unroll
        for (int j = 0; j < 4; j++)
            bg[j] = *(const bf16x8*)(Bb + (size_t)j * 16 * K + ks);
        #pragma unroll
        for (int i = 0; i < 4; i++)
            #pragma unroll
            for (int j = 0; j < 4; j++)
                acc[i][j] = __builtin_amdgcn_mfma_f32_16x16x32_bf16(
                    af[i], bg[j], acc[i][j], 0, 0, 0);
    }
    #pragma unroll
    for (int i = 0; i < 4; i++)
        #pragma unroll
        for (int j = 0; j < 4; j++)
            #pragma unroll
            for (int r = 0; r < 4; r++) {
                int m = m0 + i * 16 + quad * 4 + r;
                int n = n0 + j * 16 + l16;
                C[(size_t)m * U + n] = f2bf(acc[i][j][r]);
            }
}

// ---------------------------------------------------------------------------
// Persistent scan v5: 256 blocks x 1024 threads, cooperative.
// = v4 (single-poller + balanced dealing + fused phase5) with the two
// spin/barrier behaviors reverted to the r0-r3 proven forms:
//  * poll loops keep __builtin_amdgcn_s_sleep(1) (v4 removed it; suspect in
//    the container failure -- full-rate agent-load spin).
//  * B1 is plain __syncthreads() (r0-r3 proven); B2 stays lgkm-only (r3
//    proven).
// Ideas under test (unchanged from v4):
//  * SINGLE-POLLER: only wave 0 polls the 8 agent tags (8 pollers/batch,
//    was 128 -> 16x less load pressure on the stats lines). inv broadcast
//    via s_inv + B2.
//  * BALANCED DEALING: every block compacts the FULL batch mask (identical
//    deterministic computation, no exchange) and owns active rows with
//    rank % 8 == g -> per-block phase1 work equal +-1 row (kills per-step
//    max-of-8 Binomial straggle). Inactive rows' outputs are constant 0 ->
//    written once in prologue by slice owner.
//  * PHASE5 FUSED into next step's phase1: cov = s_cov + p*inv_prev;
//    alpha(s-1)/covl(s-1) stored there; each slot touched by exactly one
//    wave -> no extra barrier.
// Slab aliasing stays safe: first myctx store is post-poll(0), and poll(0)
// success requires all 8 blocks past their prologue (enreg staging done).
__global__ __launch_bounds__(1024, 4) void k_scan(
        const unsigned short* __restrict__ enc_bf,
        const unsigned short* __restrict__ dec_bf,
        const unsigned short* en_bf,     // aliases pctx!
        const float* __restrict__ w_c,
        const float* __restrict__ v,
        const int* __restrict__ mask,
        unsigned long long* __restrict__ stats,  // [2][B][NB]
        float* pctx,                     // aliases en_bf! per-(b,g) slabs
        float* __restrict__ out)
{
    const int blk = blockIdx.x;
    const int b = blk & 31, g = blk >> 5;    // batch's 8 blocks share an XCD
    const int tid = threadIdx.x;
    const int w = tid >> 6, lane = tid & 63;
    const int u = lane * 8;
    const float L2E = 1.4426950408889634f;

    __shared__ __align__(16) unsigned short s_enc[RPB * U];  // 128 KiB (by slot)
    __shared__ float  s_p[RPB];       // unnormalized exp2(mu*L2E) per slot
    __shared__ float  s_cov[RPB];     // coverage per slot
    __shared__ short  s_rowid[RPB];   // slot -> batch row
    __shared__ unsigned long long s_bal[16];
    __shared__ float  s_wsum[16];
    __shared__ float  s_q[4][512];    // quarter ctx partials, 8 KiB
    __shared__ float  s_inv;

    const int* maskb = mask + b * TE;
    float* alphas = out + (size_t)B * TD * (DD + DE);
    float* covl   = alphas + (size_t)B * TD * TE;

    // lane-resident w_c / v fragments
    float wc[8], vv[8];
    {
        float4 a0 = *(const float4*)&w_c[u];
        float4 a1 = *(const float4*)&w_c[u + 4];
        wc[0]=a0.x; wc[1]=a0.y; wc[2]=a0.z; wc[3]=a0.w;
        wc[4]=a1.x; wc[5]=a1.y; wc[6]=a1.z; wc[7]=a1.w;
        float4 b0 = *(const float4*)&v[u];
        float4 b1 = *(const float4*)&v[u + 4];
        vv[0]=b0.x; vv[1]=b0.y; vv[2]=b0.z; vv[3]=b0.w;
        vv[4]=b1.x; vv[5]=b1.y; vv[6]=b1.z; vv[7]=b1.w;
    }

    // ---- global active-row compaction (identical in all 8 blocks of b)
    int act = (maskb[tid] != 0);
    {
        unsigned long long bal = __ballot(act);
        if (lane == 0) s_bal[w] = bal;
        if (tid < RPB) { s_p[tid] = 0.f; s_cov[tid] = 0.f; s_rowid[tid] = 0; }
        __syncthreads();
    }
    int nact = 0, pre = 0;
    {
        #pragma unroll
        for (int ww = 0; ww < 16; ww++) {
            int c = __popcll(s_bal[ww]);
            if (ww < w) pre += c;
            nact += c;
        }
        pre += __popcll(s_bal[w] & ((1ull << lane) - 1));
        if (act && (pre & 7) == g) s_rowid[pre >> 3] = (short)tid;
    }
    const int Sblk = (nact + 7 - g) >> 3;    // assigned slots (<=128)

    // ---- zero alpha/covl for inactive rows of OWN slice, all steps (once)
    for (int t = tid; t < RPB * TD; t += 1024) {
        int rl = t & 127, s = t >> 7;
        if (maskb[g * RPB + rl] == 0) {
            size_t rowo = ((size_t)b * TD + s) * TE + g * RPB + rl;
            alphas[rowo] = 0.f;
            covl[rowo]   = 0.f;
        }
    }
    __syncthreads();   // s_rowid ready

    // ---- stage assigned rows' enc into LDS (slot-major), gather by rowid
    {
        const int slot = tid >> 3, part = tid & 7;   // 128 slots x 8 parts
        const uint4* src = (const uint4*)
            (enc_bf + ((size_t)b * TE + s_rowid[slot]) * U);
        uint4* dst = (uint4*)(s_enc + (size_t)slot * U);
        #pragma unroll
        for (int j = 0; j < 8; j++) dst[part + j * 8] = src[part + j * 8];
    }
    // ---- hoist assigned rows' en words (phase6 operands), by rowid
    const int e2 = tid & 255, q4 = tid >> 8;   // 256 e-pairs x 4 quarters
    unsigned enreg[32];
    {
        const unsigned* enw = (const unsigned*)en_bf;
        #pragma unroll
        for (int r = 0; r < 32; r++) {
            int row = s_rowid[q4 * 32 + r];
            enreg[r] = enw[((size_t)b * TE + row) * (DE / 2) + e2];
        }
    }
    // private ctx slab: this (b,g)'s dead en_bf slice (64 steps x 512 f32)
    float* myctx = pctx + ((size_t)b * 1024 + g * RPB) * 256;

    __syncthreads();   // s_enc staged

    // pipelined dec fragment
    uint4 qd = *(const uint4*)(dec_bf + ((size_t)b * TD) * U + u);

    float inv_prev = 0.f;
    for (int s = 0; s < TD; s++) {
        float df[8];
        unpack8(qd, df);

        // ---- phase 1 (+fused phase 5 of step s-1) over own slots
        float local_esum = 0.f;
        for (int i = w; i < Sblk; i += 16) {
            float pold   = s_p[i];
            float covold = s_cov[i];
            float aprev  = pold * inv_prev;
            float cov    = covold + aprev;        // cov(s)
            if (s > 0 && lane == 0) {
                size_t rowo = ((size_t)b * TD + (s - 1)) * TE + s_rowid[i];
                alphas[rowo] = aprev;
                covl[rowo]   = fminf(covold, aprev);
            }
            uint4 q = *(const uint4*)(s_enc + (size_t)i * U + u);
            float e[8]; unpack8(q, e);
            float acc = 0.f;
            #pragma unroll
            for (int j = 0; j < 8; j++)
                acc += vv[j] * tanh_fast(fmaf(cov, wc[j], e[j] + df[j]));
            acc = wave_reduce_sum(acc);
            float pe = EXP2F(acc * L2E);
            if (lane == 0) { s_p[i] = pe; s_cov[i] = cov; }
            local_esum += pe;
        }
        if (lane == 0) s_wsum[w] = local_esum;

        __syncthreads();   // B1 (proven form): s_p/s_cov/s_wsum visible

        // ---- publish (sum_g | tag s+1): wave 0 lane 0
        unsigned long long* sl = stats + ((size_t)(s & 1) * B + b) * NB;
        if (w == 0) {
            float x = (lane < 16) ? s_wsum[lane] : 0.f;
            float sg = wave_reduce_sum(x);
            if (lane == 0) {
                unsigned long long pv =
                    ((unsigned long long)__float_as_uint(sg) << 32) |
                    (unsigned)(s + 1);
                st_agent64(&sl[g], pv);
            }
        }

        // ---- prefetch next dec fragment (hides under phase6 + poll)
        {
            int sn = (s + 1 < TD) ? s + 1 : s;
            qd = *(const uint4*)(dec_bf + (((size_t)b * TD + sn) * U + u));
        }

        // ---- phase 6: unnormalized ctx partial over own 32 slots -> s_q
        {
            float a0 = 0.f, a1 = 0.f;
            #pragma unroll
            for (int r = 0; r < 32; r++) {
                float p = s_p[q4 * 32 + r];           // broadcast read
                a0 = fmaf(p, bflo(enreg[r]), a0);     // pad/masked: p==0 exact
                a1 = fmaf(p, bfhi(enreg[r]), a1);
            }
            s_q[q4][2 * e2]     = a0;
            s_q[q4][2 * e2 + 1] = a1;
        }

        // ---- SINGLE-POLLER: wave 0 polls 8 tags -> inv -> s_inv
        if (w == 0) {
            unsigned long long pv = 0;
            for (;;) {
                if (lane < NB) pv = ld_agent64(&sl[lane]);
                unsigned long long okm =
                    __ballot(lane < NB ? ((unsigned)pv == (unsigned)(s + 1)) : 1);
                if (~okm == 0ull) break;
                __builtin_amdgcn_s_sleep(1);
            }
            float tg = (lane < NB) ? __uint_as_float((unsigned)(pv >> 32)) : 0.f;
            tg = wave_reduce_sum(tg);
            if (lane == 0) s_inv = RCPF(tg);
        }

        LBAR();   // B2: s_q + s_inv visible (LDS-only; r3-proven form)

        inv_prev = s_inv;

        // ---- ctx(s) reduce + normalized plain store to private slab
        if (tid < 512) {
            float ts = s_q[0][tid] + s_q[1][tid] + s_q[2][tid] + s_q[3][tid];
            myctx[(size_t)s * 512 + tid] = ts * inv_prev;
        }
    }

    // ---- epilogue: flush alpha/covl for s = TD-1
    for (int i = w; i < Sblk; i += 16) {
        if (lane == 0) {
            float aprev = s_p[i] * inv_prev;
            size_t rowo = ((size_t)b * TD + (TD - 1)) * TE + s_rowid[i];
            alphas[rowo] = aprev;
            covl[rowo]   = fminf(s_cov[i], aprev);
        }
    }
    // myctx/alphas/covl drained at kernel boundary; k_ctx reads after.
}

// ---------------------------------------------------------------------------
// ctx final reduce: out ctx = sum over the 8 per-block partials.
// pctx[b][g] slab at float offset (b*1024+g*128)*256, laid out [s][e].
__global__ __launch_bounds__(1024) void k_ctx(
        const float* __restrict__ pctx, float* __restrict__ out)
{
    int idx = blockIdx.x * 1024 + threadIdx.x;   // 1,048,576 total
    int b = idx >> 15, rem = idx & 32767;        // rem = s*512 + e
    const float* p = pctx + (size_t)b * 262144 + rem;
    float t = 0.f;
    #pragma unroll
    for (int g = 0; g < NB; g++) t += p[(size_t)g * 32768];
    int s = rem >> 9, e = rem & 511;
    out[((size_t)b * TD + s) * (DD + DE) + DD + e] = t;
}

// ---------------------------------------------------------------------------
extern "C" void kernel_launch(void* const* d_in, const int* in_sizes, int n_in,
                              void* d_out, int out_size, void* d_ws, size_t ws_size,
                              hipStream_t stream) {
    const float* en_seq = (const float*)d_in[0];
    const float* de_seq = (const float*)d_in[1];
    const int*   mask   = (const int*)d_in[2];
    const float* W_h    = (const float*)d_in[3];
    const float* W_s    = (const float*)d_in[4];
    const float* w_c    = (const float*)d_in[5];
    const float* v      = (const float*)d_in[6];
    float* out = (float*)d_out;

    // workspace layout (~69 MiB). en_bf doubles as the per-block ctx-partial
    // slab during k_scan (each block's 128-KiB en slice is dead after the
    // batch-wide enreg staging, which completes before the first tag round).
    unsigned short* enc_bf = (unsigned short*)d_ws;        // B*TE*U  bf16 = 32 MiB
    unsigned short* en_bf  = enc_bf + (size_t)B * TE * U;  // B*TE*DE bf16 = 32 MiB
    unsigned short* dec_bf = en_bf  + (size_t)B * TE * DE; // B*TD*U  bf16 = 2 MiB
    unsigned short* Wh_t   = dec_bf + (size_t)B * TD * U;  // 512*512 bf16 = 0.5 MiB
    unsigned short* de_bf  = Wh_t   + (size_t)K * U;       // B*TD*DD bf16 = 2 MiB
    unsigned short* Ws_t   = de_bf  + (size_t)B * TD * DD; // 0.5 MiB
    unsigned long long* stats =
        (unsigned long long*)(Ws_t + (size_t)K * U);       // 512 u64
    float* pctx = (float*)en_bf;                           // alias

    k_prep<<<18562, 256, 0, stream>>>((const float4*)en_seq, (ushort4*)en_bf,
                                      (const float4*)de_seq, (ushort4*)de_bf,
                                      (float4*)out, W_h, Wh_t, W_s, Ws_t, stats);
    k_mfma<<<dim3(4, 272), 256, 0, stream>>>(en_bf, Wh_t, enc_bf,
                                             de_bf, Ws_t, dec_bf);

    void* args[] = { (void*)&enc_bf, (void*)&dec_bf, (void*)&en_bf,
                     (void*)&w_c, (void*)&v, (void*)&mask,
                     (void*)&stats, (void*)&pctx, (void*)&out };
    hipLaunchCooperativeKernel((const void*)k_scan, dim3(256), dim3(1024),
                               args, 0, stream);

    k_ctx<<<1024, 1024, 0, stream>>>(pctx, out);
}

// Round 6
// 547.610 us; speedup vs baseline: 1.4135x; 1.0420x over previous
//
#include <hip/hip_runtime.h>
#include <float.h>

// Problem constants
#define B   32
#define TE  1024
#define TD  64
#define DE  512
#define DD  512
#define U   512
#define K   512   // == DE == DD
#define NB  8     // blocks per batch (256-block coop launch: proven geometry)
#define RPB 128   // t-rows per block (slice size for outputs/slab)

#if __has_builtin(__builtin_amdgcn_exp2f)
#define EXP2F __builtin_amdgcn_exp2f
#else
#define EXP2F exp2f
#endif
#if __has_builtin(__builtin_amdgcn_rcpf)
#define RCPF __builtin_amdgcn_rcpf
#else
#define RCPF(x) (1.0f / (x))
#endif

#define TANH_C 2.8853900817779268f   // 2*log2(e)
#define L2E    1.4426950408889634f

typedef __attribute__((ext_vector_type(8))) short bf16x8;  // 8 bf16 = 4 VGPRs
typedef __attribute__((ext_vector_type(4))) float f32x4;

__device__ __forceinline__ float wave_reduce_sum(float v) {
    #pragma unroll
    for (int o = 32; o; o >>= 1) v += __shfl_xor(v, o, 64);
    return v;
}

// f32 -> bf16 RNE
__device__ __forceinline__ unsigned short f2bf(float f) {
    unsigned u = __float_as_uint(f);
    unsigned r = (u + 0x7fffu + ((u >> 16) & 1u)) >> 16;
    return (unsigned short)r;
}
__device__ __forceinline__ float bflo(unsigned x) { return __uint_as_float(x << 16); }
__device__ __forceinline__ float bfhi(unsigned x) { return __uint_as_float(x & 0xffff0000u); }
__device__ __forceinline__ void unpack8(uint4 q, float* f) {
    f[0] = bflo(q.x); f[1] = bfhi(q.x); f[2] = bflo(q.y); f[3] = bfhi(q.y);
    f[4] = bflo(q.z); f[5] = bfhi(q.z); f[6] = bflo(q.w); f[7] = bfhi(q.w);
}

// relaxed agent-scope accessors (tag exchange only)
__device__ __forceinline__ unsigned long long ld_agent64(const unsigned long long* p) {
    return __hip_atomic_load(p, __ATOMIC_RELAXED, __HIP_MEMORY_SCOPE_AGENT);
}
__device__ __forceinline__ void st_agent64(unsigned long long* p, unsigned long long v) {
    __hip_atomic_store(p, v, __ATOMIC_RELAXED, __HIP_MEMORY_SCOPE_AGENT);
}

// LDS-only barrier: no vmcnt drain (loop has no intra-kernel vmem reader)
#define LBAR() do { \
    asm volatile("s_waitcnt lgkmcnt(0)" ::: "memory"); \
    __builtin_amdgcn_s_barrier(); \
    __builtin_amdgcn_sched_barrier(0); \
} while (0)

// ---------------------------------------------------------------------------
// Fused prep: en cast [0,16384) | de cast [16384,17408) | pass [17408,18432)
// | W transposes [18432,18560) | stats init [18560,18562). One launch.
__global__ __launch_bounds__(256) void k_prep(
        const float4* __restrict__ en_seq, ushort4* __restrict__ en_bf,
        const float4* __restrict__ de_seq, ushort4* __restrict__ de_bf,
        float4* __restrict__ outp,
        const float* __restrict__ W_h, unsigned short* __restrict__ Wh_t,
        const float* __restrict__ W_s, unsigned short* __restrict__ Ws_t,
        unsigned long long* __restrict__ stats)
{
    __shared__ float t[64][65];
    const int blk = blockIdx.x;
    const int tid = threadIdx.x;
    if (blk < 16384) {                       // en_seq f32 -> bf16
        size_t i = (size_t)blk * 256 + tid;
        float4 f = en_seq[i];
        ushort4 r; r.x = f2bf(f.x); r.y = f2bf(f.y); r.z = f2bf(f.z); r.w = f2bf(f.w);
        en_bf[i] = r;
    } else if (blk < 17408) {                // de_seq f32 -> bf16
        size_t i = (size_t)(blk - 16384) * 256 + tid;
        float4 f = de_seq[i];
        ushort4 r; r.x = f2bf(f.x); r.y = f2bf(f.y); r.z = f2bf(f.z); r.w = f2bf(f.w);
        de_bf[i] = r;
    } else if (blk < 18432) {                // de_seq passthrough -> out[:,:,0:DD]
        size_t i = (size_t)(blk - 17408) * 256 + tid;
        size_t r = i >> 7, c = i & 127;
        outp[r * 256 + c] = de_seq[i];
    } else if (blk < 18560) {                // W transpose+cast: Wt[n][k]=W[k][n]
        int id = blk - 18432;
        const float* W = (id < 64) ? W_h : W_s;
        unsigned short* Wt = (id < 64) ? Wh_t : Ws_t;
        int bid = id & 63;
        const int bx = bid & 7, by = bid >> 3;
        const int lx = tid & 63, ly = tid >> 6;
        #pragma unroll
        for (int i = 0; i < 64; i += 4)
            t[ly + i][lx] = W[(size_t)(by * 64 + ly + i) * 512 + bx * 64 + lx];
        __syncthreads();
        #pragma unroll
        for (int i = 0; i < 64; i += 4)
            Wt[(size_t)(bx * 64 + ly + i) * 512 + by * 64 + lx] = f2bf(t[lx][ly + i]);
    } else {                                 // stats init (512 u64)
        int i = (blk - 18560) * 256 + tid;
        stats[i] = 0ull;
    }
}

// ---------------------------------------------------------------------------
// Unified MFMA GEMM: C_bf16[M,512] = A_bf16[M,512] @ Wt_bf16[n][k]^T.
// grid (4, 272): y<256 -> enc (M=32768), y>=256 -> dec (M=2048).
__global__ __launch_bounds__(256) void k_mfma(
        const unsigned short* __restrict__ Ae, const unsigned short* __restrict__ Be,
        unsigned short* __restrict__ Ce,
        const unsigned short* __restrict__ Ad, const unsigned short* __restrict__ Bd,
        unsigned short* __restrict__ Cd)
{
    const int tid = threadIdx.x;
    const int w = tid >> 6, lane = tid & 63;
    const int quad = lane >> 4, l16 = lane & 15;
    const short* A; const short* Bt; unsigned short* C; int mb;
    if (blockIdx.y < 256) {
        A = (const short*)Ae; Bt = (const short*)Be; C = Ce; mb = blockIdx.y * 128;
    } else {
        A = (const short*)Ad; Bt = (const short*)Bd; C = Cd; mb = (blockIdx.y - 256) * 128;
    }
    const int m0 = mb + (w >> 1) * 64;
    const int n0 = blockIdx.x * 128 + (w & 1) * 64;

    const short* Ab = A  + (size_t)(m0 + l16) * K + quad * 8;
    const short* Bb = Bt + (size_t)(n0 + l16) * K + quad * 8;

    f32x4 acc[4][4] = {};
    for (int ks = 0; ks < K; ks += 32) {
        bf16x8 af[4], bg[4];
        #pragma unroll
        for (int i = 0; i < 4; i++)
            af[i] = *(const bf16x8*)(Ab + (size_t)i * 16 * K + ks);
        #pragma unroll
        for (int j = 0; j < 4; j++)
            bg[j] = *(const bf16x8*)(Bb + (size_t)j * 16 * K + ks);
        #pragma unroll
        for (int i = 0; i < 4; i++)
            #pragma unroll
            for (int j = 0; j < 4; j++)
                acc[i][j] = __builtin_amdgcn_mfma_f32_16x16x32_bf16(
                    af[i], bg[j], acc[i][j], 0, 0, 0);
    }
    #pragma unroll
    for (int i = 0; i < 4; i++)
        #pragma unroll
        for (int j = 0; j < 4; j++)
            #pragma unroll
            for (int r = 0; r < 4; r++) {
                int m = m0 + i * 16 + quad * 4 + r;
                int n = n0 + j * 16 + l16;
                C[(size_t)m * U + n] = f2bf(acc[i][j][r]);
            }
}

// ---------------------------------------------------------------------------
// Persistent scan v6: 256 blocks x 1024 threads, cooperative.
// = v5 (proven: single-poller + balanced dealing + fused phase5, 380us) with
// issue-path reductions; sync skeleton unchanged:
//  * tanh strength-reduction: sum_j vv_j*tanh(x_j) = vsum - 2*sum vv_j*
//    rcp(exp2(c*x_j)+1), with c=2log2(e) folded into prescaled wcc/dfc and
//    one fma on the enc element. Inner j: 6 ops (was 8), 2 trans unchanged.
//    Per-lane vsum fma keeps the original per-lane cancellation (numerics).
//  * phase6 reads s_p via 8x ds_read_b128 (was 32x b32): 4x fewer LDS instrs
//    on the per-step critical LDS path.
//  * B1 is now lgkm-only (LBAR, r3/r5-proven form): the loop has no
//    intra-kernel vmem reader, so __syncthreads' vmcnt(0) drain was waste.
//  * publish reduce: 4 shfl (16 values), was 6.
__global__ __launch_bounds__(1024, 4) void k_scan(
        const unsigned short* __restrict__ enc_bf,
        const unsigned short* __restrict__ dec_bf,
        const unsigned short* en_bf,     // aliases pctx!
        const float* __restrict__ w_c,
        const float* __restrict__ v,
        const int* __restrict__ mask,
        unsigned long long* __restrict__ stats,  // [2][B][NB]
        float* pctx,                     // aliases en_bf! per-(b,g) slabs
        float* __restrict__ out)
{
    const int blk = blockIdx.x;
    const int b = blk & 31, g = blk >> 5;    // batch's 8 blocks share an XCD
    const int tid = threadIdx.x;
    const int w = tid >> 6, lane = tid & 63;
    const int u = lane * 8;

    __shared__ __align__(16) unsigned short s_enc[RPB * U];  // 128 KiB (by slot)
    __shared__ __align__(16) float s_p[RPB];  // unnormalized exp2(mu*L2E)/slot
    __shared__ float  s_cov[RPB];     // coverage per slot
    __shared__ short  s_rowid[RPB];   // slot -> batch row
    __shared__ unsigned long long s_bal[16];
    __shared__ float  s_wsum[16];
    __shared__ float  s_q[4][512];    // quarter ctx partials, 8 KiB
    __shared__ float  s_inv;

    const int* maskb = mask + b * TE;
    float* alphas = out + (size_t)B * TD * (DD + DE);
    float* covl   = alphas + (size_t)B * TD * TE;

    // lane-resident fragments: wcc = w_c*c (prescaled), vv, vsum (per-lane)
    float wcc[8], vv[8], vsuml;
    {
        float4 a0 = *(const float4*)&w_c[u];
        float4 a1 = *(const float4*)&w_c[u + 4];
        wcc[0]=a0.x*TANH_C; wcc[1]=a0.y*TANH_C; wcc[2]=a0.z*TANH_C; wcc[3]=a0.w*TANH_C;
        wcc[4]=a1.x*TANH_C; wcc[5]=a1.y*TANH_C; wcc[6]=a1.z*TANH_C; wcc[7]=a1.w*TANH_C;
        float4 b0 = *(const float4*)&v[u];
        float4 b1 = *(const float4*)&v[u + 4];
        vv[0]=b0.x; vv[1]=b0.y; vv[2]=b0.z; vv[3]=b0.w;
        vv[4]=b1.x; vv[5]=b1.y; vv[6]=b1.z; vv[7]=b1.w;
        vsuml = ((vv[0]+vv[1])+(vv[2]+vv[3])) + ((vv[4]+vv[5])+(vv[6]+vv[7]));
    }

    // ---- global active-row compaction (identical in all 8 blocks of b)
    int act = (maskb[tid] != 0);
    {
        unsigned long long bal = __ballot(act);
        if (lane == 0) s_bal[w] = bal;
        if (tid < RPB) { s_p[tid] = 0.f; s_cov[tid] = 0.f; s_rowid[tid] = 0; }
        __syncthreads();
    }
    int nact = 0, pre = 0;
    {
        #pragma unroll
        for (int ww = 0; ww < 16; ww++) {
            int c = __popcll(s_bal[ww]);
            if (ww < w) pre += c;
            nact += c;
        }
        pre += __popcll(s_bal[w] & ((1ull << lane) - 1));
        if (act && (pre & 7) == g) s_rowid[pre >> 3] = (short)tid;
    }
    const int Sblk = (nact + 7 - g) >> 3;    // assigned slots (<=128)

    // ---- zero alpha/covl for inactive rows of OWN slice, all steps (once)
    for (int t = tid; t < RPB * TD; t += 1024) {
        int rl = t & 127, s = t >> 7;
        if (maskb[g * RPB + rl] == 0) {
            size_t rowo = ((size_t)b * TD + s) * TE + g * RPB + rl;
            alphas[rowo] = 0.f;
            covl[rowo]   = 0.f;
        }
    }
    __syncthreads();   // s_rowid ready

    // ---- stage assigned rows' enc into LDS (slot-major), gather by rowid
    {
        const int slot = tid >> 3, part = tid & 7;   // 128 slots x 8 parts
        const uint4* src = (const uint4*)
            (enc_bf + ((size_t)b * TE + s_rowid[slot]) * U);
        uint4* dst = (uint4*)(s_enc + (size_t)slot * U);
        #pragma unroll
        for (int j = 0; j < 8; j++) dst[part + j * 8] = src[part + j * 8];
    }
    // ---- hoist assigned rows' en words (phase6 operands), by rowid
    const int e2 = tid & 255, q4 = tid >> 8;   // 256 e-pairs x 4 quarters
    unsigned enreg[32];
    {
        const unsigned* enw = (const unsigned*)en_bf;
        #pragma unroll
        for (int r = 0; r < 32; r++) {
            int row = s_rowid[q4 * 32 + r];
            enreg[r] = enw[((size_t)b * TE + row) * (DE / 2) + e2];
        }
    }
    // private ctx slab: this (b,g)'s dead en_bf slice (64 steps x 512 f32)
    float* myctx = pctx + ((size_t)b * 1024 + g * RPB) * 256;

    __syncthreads();   // s_enc staged

    // pipelined dec fragment
    uint4 qd = *(const uint4*)(dec_bf + ((size_t)b * TD) * U + u);

    float inv_prev = 0.f;
    for (int s = 0; s < TD; s++) {
        // dfc = df * c (prescaled for the folded tanh argument)
        float dfc[8];
        unpack8(qd, dfc);
        #pragma unroll
        for (int j = 0; j < 8; j++) dfc[j] *= TANH_C;

        // ---- phase 1 (+fused phase 5 of step s-1) over own slots
        float local_esum = 0.f;
        for (int i = w; i < Sblk; i += 16) {
            float pold   = s_p[i];
            float covold = s_cov[i];
            float aprev  = pold * inv_prev;
            float cov    = covold + aprev;        // cov(s)
            if (s > 0 && lane == 0) {
                size_t rowo = ((size_t)b * TD + (s - 1)) * TE + s_rowid[i];
                alphas[rowo] = aprev;
                covl[rowo]   = fminf(covold, aprev);
            }
            uint4 q = *(const uint4*)(s_enc + (size_t)i * U + u);
            float e[8]; unpack8(q, e);
            float acc2 = 0.f;
            #pragma unroll
            for (int j = 0; j < 8; j++) {
                float arg = fmaf(cov, wcc[j], fmaf(e[j], TANH_C, dfc[j]));
                acc2 = fmaf(vv[j], RCPF(EXP2F(arg) + 1.0f), acc2);
            }
            // per-lane mu partial = vsum_l - 2*acc2_l (original cancellation)
            float part = fmaf(acc2, -2.0f, vsuml);
            part = wave_reduce_sum(part);         // = mu (wave-uniform)
            float pe = EXP2F(part * L2E);
            if (lane == 0) { s_p[i] = pe; s_cov[i] = cov; }
            local_esum += pe;
        }
        if (lane == 0) s_wsum[w] = local_esum;

        LBAR();   // B1: s_p/s_cov/s_wsum visible (LDS-only; no vmcnt drain)

        // ---- publish (sum_g | tag s+1): wave 0 lane 0
        unsigned long long* sl = stats + ((size_t)(s & 1) * B + b) * NB;
        if (w == 0) {
            float x = (lane < 16) ? s_wsum[lane] : 0.f;
            x += __shfl_xor(x, 8, 64);
            x += __shfl_xor(x, 4, 64);
            x += __shfl_xor(x, 2, 64);
            x += __shfl_xor(x, 1, 64);            // lane0: sum of 16
            if (lane == 0) {
                unsigned long long pv =
                    ((unsigned long long)__float_as_uint(x) << 32) |
                    (unsigned)(s + 1);
                st_agent64(&sl[g], pv);
            }
        }

        // ---- prefetch next dec fragment (hides under phase6 + poll)
        {
            int sn = (s + 1 < TD) ? s + 1 : s;
            qd = *(const uint4*)(dec_bf + (((size_t)b * TD + sn) * U + u));
        }

        // ---- phase 6: unnormalized ctx partial over own 32 slots -> s_q
        //      (s_p read as 8x float4: 4x fewer LDS instructions)
        {
            const float4* pb = (const float4*)&s_p[q4 * 32];
            float a0 = 0.f, a1 = 0.f;
            #pragma unroll
            for (int k = 0; k < 8; k++) {
                float4 pp = pb[k];
                a0 = fmaf(pp.x, bflo(enreg[4*k]),   a0);
                a1 = fmaf(pp.x, bfhi(enreg[4*k]),   a1);
                a0 = fmaf(pp.y, bflo(enreg[4*k+1]), a0);
                a1 = fmaf(pp.y, bfhi(enreg[4*k+1]), a1);
                a0 = fmaf(pp.z, bflo(enreg[4*k+2]), a0);
                a1 = fmaf(pp.z, bfhi(enreg[4*k+2]), a1);
                a0 = fmaf(pp.w, bflo(enreg[4*k+3]), a0);
                a1 = fmaf(pp.w, bfhi(enreg[4*k+3]), a1);
            }
            s_q[q4][2 * e2]     = a0;
            s_q[q4][2 * e2 + 1] = a1;
        }

        // ---- SINGLE-POLLER: wave 0 polls 8 tags -> inv -> s_inv
        if (w == 0) {
            unsigned long long pv = 0;
            for (;;) {
                if (lane < NB) pv = ld_agent64(&sl[lane]);
                unsigned long long okm =
                    __ballot(lane < NB ? ((unsigned)pv == (unsigned)(s + 1)) : 1);
                if (~okm == 0ull) break;
                __builtin_amdgcn_s_sleep(1);
            }
            float tg = (lane < NB) ? __uint_as_float((unsigned)(pv >> 32)) : 0.f;
            tg = wave_reduce_sum(tg);
            if (lane == 0) s_inv = RCPF(tg);
        }

        LBAR();   // B2: s_q + s_inv visible (LDS-only)

        inv_prev = s_inv;

        // ---- ctx(s) reduce + normalized plain store to private slab
        if (tid < 512) {
            float ts = s_q[0][tid] + s_q[1][tid] + s_q[2][tid] + s_q[3][tid];
            myctx[(size_t)s * 512 + tid] = ts * inv_prev;
        }
    }

    // ---- epilogue: flush alpha/covl for s = TD-1
    for (int i = w; i < Sblk; i += 16) {
        if (lane == 0) {
            float aprev = s_p[i] * inv_prev;
            size_t rowo = ((size_t)b * TD + (TD - 1)) * TE + s_rowid[i];
            alphas[rowo] = aprev;
            covl[rowo]   = fminf(s_cov[i], aprev);
        }
    }
    // myctx/alphas/covl drained at kernel boundary; k_ctx reads after.
}

// ---------------------------------------------------------------------------
// ctx final reduce: out ctx = sum over the 8 per-block partials.
// pctx[b][g] slab at float offset (b*1024+g*128)*256, laid out [s][e].
__global__ __launch_bounds__(1024) void k_ctx(
        const float* __restrict__ pctx, float* __restrict__ out)
{
    int idx = blockIdx.x * 1024 + threadIdx.x;   // 1,048,576 total
    int b = idx >> 15, rem = idx & 32767;        // rem = s*512 + e
    const float* p = pctx + (size_t)b * 262144 + rem;
    float t = 0.f;
    #pragma unroll
    for (int g = 0; g < NB; g++) t += p[(size_t)g * 32768];
    int s = rem >> 9, e = rem & 511;
    out[((size_t)b * TD + s) * (DD + DE) + DD + e] = t;
}

// ---------------------------------------------------------------------------
extern "C" void kernel_launch(void* const* d_in, const int* in_sizes, int n_in,
                              void* d_out, int out_size, void* d_ws, size_t ws_size,
                              hipStream_t stream) {
    const float* en_seq = (const float*)d_in[0];
    const float* de_seq = (const float*)d_in[1];
    const int*   mask   = (const int*)d_in[2];
    const float* W_h    = (const float*)d_in[3];
    const float* W_s    = (const float*)d_in[4];
    const float* w_c    = (const float*)d_in[5];
    const float* v      = (const float*)d_in[6];
    float* out = (float*)d_out;

    // workspace layout (~69 MiB). en_bf doubles as the per-block ctx-partial
    // slab during k_scan (each block's 128-KiB en slice is dead after the
    // batch-wide enreg staging, which completes before the first tag round).
    unsigned short* enc_bf = (unsigned short*)d_ws;        // B*TE*U  bf16 = 32 MiB
    unsigned short* en_bf  = enc_bf + (size_t)B * TE * U;  // B*TE*DE bf16 = 32 MiB
    unsigned short* dec_bf = en_bf  + (size_t)B * TE * DE; // B*TD*U  bf16 = 2 MiB
    unsigned short* Wh_t   = dec_bf + (size_t)B * TD * U;  // 512*512 bf16 = 0.5 MiB
    unsigned short* de_bf  = Wh_t   + (size_t)K * U;       // B*TD*DD bf16 = 2 MiB
    unsigned short* Ws_t   = de_bf  + (size_t)B * TD * DD; // 0.5 MiB
    unsigned long long* stats =
        (unsigned long long*)(Ws_t + (size_t)K * U);       // 512 u64
    float* pctx = (float*)en_bf;                           // alias

    k_prep<<<18562, 256, 0, stream>>>((const float4*)en_seq, (ushort4*)en_bf,
                                      (const float4*)de_seq, (ushort4*)de_bf,
                                      (float4*)out, W_h, Wh_t, W_s, Ws_t, stats);
    k_mfma<<<dim3(4, 272), 256, 0, stream>>>(en_bf, Wh_t, enc_bf,
                                             de_bf, Ws_t, dec_bf);

    void* args[] = { (void*)&enc_bf, (void*)&dec_bf, (void*)&en_bf,
                     (void*)&w_c, (void*)&v, (void*)&mask,
                     (void*)&stats, (void*)&pctx, (void*)&out };
    hipLaunchCooperativeKernel((const void*)k_scan, dim3(256), dim3(1024),
                               args, 0, stream);

    k_ctx<<<1024, 1024, 0, stream>>>(pctx, out);
}

// Round 8
// 544.605 us; speedup vs baseline: 1.4213x; 1.0055x over previous
//
#include <hip/hip_runtime.h>
#include <float.h>

// Problem constants
#define B   32
#define TE  1024
#define TD  64
#define DE  512
#define DD  512
#define U   512
#define K   512   // == DE == DD
#define NB  8     // blocks per batch (256-block coop launch: proven geometry)
#define RPB 128   // t-rows per block (slice size for outputs/slab)

#if __has_builtin(__builtin_amdgcn_exp2f)
#define EXP2F __builtin_amdgcn_exp2f
#else
#define EXP2F exp2f
#endif
#if __has_builtin(__builtin_amdgcn_rcpf)
#define RCPF __builtin_amdgcn_rcpf
#else
#define RCPF(x) (1.0f / (x))
#endif

#define TANH_C 2.8853900817779268f   // 2*log2(e)
#define L2E    1.4426950408889634f

typedef __attribute__((ext_vector_type(8))) short bf16x8;  // 8 bf16 = 4 VGPRs
typedef __attribute__((ext_vector_type(4))) float f32x4;

__device__ __forceinline__ float wave_reduce_sum(float v) {
    #pragma unroll
    for (int o = 32; o; o >>= 1) v += __shfl_xor(v, o, 64);
    return v;
}

// f32 -> bf16 RNE
__device__ __forceinline__ unsigned short f2bf(float f) {
    unsigned u = __float_as_uint(f);
    unsigned r = (u + 0x7fffu + ((u >> 16) & 1u)) >> 16;
    return (unsigned short)r;
}
__device__ __forceinline__ float bflo(unsigned x) { return __uint_as_float(x << 16); }
__device__ __forceinline__ float bfhi(unsigned x) { return __uint_as_float(x & 0xffff0000u); }
__device__ __forceinline__ void unpack8(uint4 q, float* f) {
    f[0] = bflo(q.x); f[1] = bfhi(q.x); f[2] = bflo(q.y); f[3] = bfhi(q.y);
    f[4] = bflo(q.z); f[5] = bfhi(q.z); f[6] = bflo(q.w); f[7] = bfhi(q.w);
}

// relaxed agent-scope accessors (tag exchange only)
__device__ __forceinline__ unsigned long long ld_agent64(const unsigned long long* p) {
    return __hip_atomic_load(p, __ATOMIC_RELAXED, __HIP_MEMORY_SCOPE_AGENT);
}
__device__ __forceinline__ void st_agent64(unsigned long long* p, unsigned long long v) {
    __hip_atomic_store(p, v, __ATOMIC_RELAXED, __HIP_MEMORY_SCOPE_AGENT);
}

// LDS-only barrier: no vmcnt drain (loop has no intra-kernel vmem reader)
#define LBAR() do { \
    asm volatile("s_waitcnt lgkmcnt(0)" ::: "memory"); \
    __builtin_amdgcn_s_barrier(); \
    __builtin_amdgcn_sched_barrier(0); \
} while (0)

// ---------------------------------------------------------------------------
// Fused prep, GRID-STRIDED over 18562 virtual blocks (dispatch-overhead cut):
// en cast [0,16384) | de cast [16384,17408) | pass [17408,18432) |
// W transposes [18432,18560) | stats init [18560,18562).
// Each physical block hits the W branch at most once (128 items < stride),
// so the LDS transpose tile is never reused -> no extra sync needed.
__global__ __launch_bounds__(256) void k_prep(
        const float4* __restrict__ en_seq, ushort4* __restrict__ en_bf,
        const float4* __restrict__ de_seq, ushort4* __restrict__ de_bf,
        float4* __restrict__ outp,
        const float* __restrict__ W_h, unsigned short* __restrict__ Wh_t,
        const float* __restrict__ W_s, unsigned short* __restrict__ Ws_t,
        unsigned long long* __restrict__ stats)
{
    __shared__ float t[64][65];
    const int tid = threadIdx.x;
    for (int blk = blockIdx.x; blk < 18562; blk += 2048) {
        if (blk < 16384) {                       // en_seq f32 -> bf16
            size_t i = (size_t)blk * 256 + tid;
            float4 f = en_seq[i];
            ushort4 r; r.x = f2bf(f.x); r.y = f2bf(f.y); r.z = f2bf(f.z); r.w = f2bf(f.w);
            en_bf[i] = r;
        } else if (blk < 17408) {                // de_seq f32 -> bf16
            size_t i = (size_t)(blk - 16384) * 256 + tid;
            float4 f = de_seq[i];
            ushort4 r; r.x = f2bf(f.x); r.y = f2bf(f.y); r.z = f2bf(f.z); r.w = f2bf(f.w);
            de_bf[i] = r;
        } else if (blk < 18432) {                // de_seq passthrough -> out[:,:,0:DD]
            size_t i = (size_t)(blk - 17408) * 256 + tid;
            size_t r = i >> 7, c = i & 127;
            outp[r * 256 + c] = de_seq[i];
        } else if (blk < 18560) {                // W transpose+cast: Wt[n][k]=W[k][n]
            int id = blk - 18432;
            const float* W = (id < 64) ? W_h : W_s;
            unsigned short* Wt = (id < 64) ? Wh_t : Ws_t;
            int bid = id & 63;
            const int bx = bid & 7, by = bid >> 3;
            const int lx = tid & 63, ly = tid >> 6;
            #pragma unroll
            for (int i = 0; i < 64; i += 4)
                t[ly + i][lx] = W[(size_t)(by * 64 + ly + i) * 512 + bx * 64 + lx];
            __syncthreads();
            #pragma unroll
            for (int i = 0; i < 64; i += 4)
                Wt[(size_t)(bx * 64 + ly + i) * 512 + by * 64 + lx] = f2bf(t[lx][ly + i]);
        } else {                                 // stats init (512 u64)
            int i = (blk - 18560) * 256 + tid;
            stats[i] = 0ull;
        }
    }
}

// ---------------------------------------------------------------------------
// Unified MFMA GEMM: C_bf16[M,512] = A_bf16[M,512] @ Wt_bf16[n][k]^T.
// grid (4, 272): y<256 -> enc (M=32768), y>=256 -> dec (M=2048).
__global__ __launch_bounds__(256) void k_mfma(
        const unsigned short* __restrict__ Ae, const unsigned short* __restrict__ Be,
        unsigned short* __restrict__ Ce,
        const unsigned short* __restrict__ Ad, const unsigned short* __restrict__ Bd,
        unsigned short* __restrict__ Cd)
{
    const int tid = threadIdx.x;
    const int w = tid >> 6, lane = tid & 63;
    const int quad = lane >> 4, l16 = lane & 15;
    const short* A; const short* Bt; unsigned short* C; int mb;
    if (blockIdx.y < 256) {
        A = (const short*)Ae; Bt = (const short*)Be; C = Ce; mb = blockIdx.y * 128;
    } else {
        A = (const short*)Ad; Bt = (const short*)Bd; C = Cd; mb = (blockIdx.y - 256) * 128;
    }
    const int m0 = mb + (w >> 1) * 64;
    const int n0 = blockIdx.x * 128 + (w & 1) * 64;

    const short* Ab = A  + (size_t)(m0 + l16) * K + quad * 8;
    const short* Bb = Bt + (size_t)(n0 + l16) * K + quad * 8;

    f32x4 acc[4][4] = {};
    for (int ks = 0; ks < K; ks += 32) {
        bf16x8 af[4], bg[4];
        #pragma unroll
        for (int i = 0; i < 4; i++)
            af[i] = *(const bf16x8*)(Ab + (size_t)i * 16 * K + ks);
        #pragma unroll
        for (int j = 0; j < 4; j++)
            bg[j] = *(const bf16x8*)(Bb + (size_t)j * 16 * K + ks);
        #pragma unroll
        for (int i = 0; i < 4; i++)
            #pragma unroll
            for (int j = 0; j < 4; j++)
                acc[i][j] = __builtin_amdgcn_mfma_f32_16x16x32_bf16(
                    af[i], bg[j], acc[i][j], 0, 0, 0);
    }
    #pragma unroll
    for (int i = 0; i < 4; i++)
        #pragma unroll
        for (int j = 0; j < 4; j++)
            #pragma unroll
            for (int r = 0; r < 4; r++) {
                int m = m0 + i * 16 + quad * 4 + r;
                int n = n0 + j * 16 + l16;
                C[(size_t)m * U + n] = f2bf(acc[i][j][r]);
            }
}

// ---------------------------------------------------------------------------
// Persistent scan v6 (byte-identical to the proven 351us version):
// 256 blocks x 1024 threads, cooperative. Single-poller + balanced dealing +
// fused phase5 + tanh strength-reduction + LDS-only barriers.
__global__ __launch_bounds__(1024, 4) void k_scan(
        const unsigned short* __restrict__ enc_bf,
        const unsigned short* __restrict__ dec_bf,
        const unsigned short* en_bf,     // aliases pctx!
        const float* __restrict__ w_c,
        const float* __restrict__ v,
        const int* __restrict__ mask,
        unsigned long long* __restrict__ stats,  // [2][B][NB]
        float* pctx,                     // aliases en_bf! per-(b,g) slabs
        float* __restrict__ out)
{
    const int blk = blockIdx.x;
    const int b = blk & 31, g = blk >> 5;    // batch's 8 blocks share an XCD
    const int tid = threadIdx.x;
    const int w = tid >> 6, lane = tid & 63;
    const int u = lane * 8;

    __shared__ __align__(16) unsigned short s_enc[RPB * U];  // 128 KiB (by slot)
    __shared__ __align__(16) float s_p[RPB];  // unnormalized exp2(mu*L2E)/slot
    __shared__ float  s_cov[RPB];     // coverage per slot
    __shared__ short  s_rowid[RPB];   // slot -> batch row
    __shared__ unsigned long long s_bal[16];
    __shared__ float  s_wsum[16];
    __shared__ float  s_q[4][512];    // quarter ctx partials, 8 KiB
    __shared__ float  s_inv;

    const int* maskb = mask + b * TE;
    float* alphas = out + (size_t)B * TD * (DD + DE);
    float* covl   = alphas + (size_t)B * TD * TE;

    // lane-resident fragments: wcc = w_c*c (prescaled), vv, vsum (per-lane)
    float wcc[8], vv[8], vsuml;
    {
        float4 a0 = *(const float4*)&w_c[u];
        float4 a1 = *(const float4*)&w_c[u + 4];
        wcc[0]=a0.x*TANH_C; wcc[1]=a0.y*TANH_C; wcc[2]=a0.z*TANH_C; wcc[3]=a0.w*TANH_C;
        wcc[4]=a1.x*TANH_C; wcc[5]=a1.y*TANH_C; wcc[6]=a1.z*TANH_C; wcc[7]=a1.w*TANH_C;
        float4 b0 = *(const float4*)&v[u];
        float4 b1 = *(const float4*)&v[u + 4];
        vv[0]=b0.x; vv[1]=b0.y; vv[2]=b0.z; vv[3]=b0.w;
        vv[4]=b1.x; vv[5]=b1.y; vv[6]=b1.z; vv[7]=b1.w;
        vsuml = ((vv[0]+vv[1])+(vv[2]+vv[3])) + ((vv[4]+vv[5])+(vv[6]+vv[7]));
    }

    // ---- global active-row compaction (identical in all 8 blocks of b)
    int act = (maskb[tid] != 0);
    {
        unsigned long long bal = __ballot(act);
        if (lane == 0) s_bal[w] = bal;
        if (tid < RPB) { s_p[tid] = 0.f; s_cov[tid] = 0.f; s_rowid[tid] = 0; }
        __syncthreads();
    }
    int nact = 0, pre = 0;
    {
        #pragma unroll
        for (int ww = 0; ww < 16; ww++) {
            int c = __popcll(s_bal[ww]);
            if (ww < w) pre += c;
            nact += c;
        }
        pre += __popcll(s_bal[w] & ((1ull << lane) - 1));
        if (act && (pre & 7) == g) s_rowid[pre >> 3] = (short)tid;
    }
    const int Sblk = (nact + 7 - g) >> 3;    // assigned slots (<=128)

    // ---- zero alpha/covl for inactive rows of OWN slice, all steps (once)
    for (int t = tid; t < RPB * TD; t += 1024) {
        int rl = t & 127, s = t >> 7;
        if (maskb[g * RPB + rl] == 0) {
            size_t rowo = ((size_t)b * TD + s) * TE + g * RPB + rl;
            alphas[rowo] = 0.f;
            covl[rowo]   = 0.f;
        }
    }
    __syncthreads();   // s_rowid ready

    // ---- stage assigned rows' enc into LDS (slot-major), gather by rowid
    {
        const int slot = tid >> 3, part = tid & 7;   // 128 slots x 8 parts
        const uint4* src = (const uint4*)
            (enc_bf + ((size_t)b * TE + s_rowid[slot]) * U);
        uint4* dst = (uint4*)(s_enc + (size_t)slot * U);
        #pragma unroll
        for (int j = 0; j < 8; j++) dst[part + j * 8] = src[part + j * 8];
    }
    // ---- hoist assigned rows' en words (phase6 operands), by rowid
    const int e2 = tid & 255, q4 = tid >> 8;   // 256 e-pairs x 4 quarters
    unsigned enreg[32];
    {
        const unsigned* enw = (const unsigned*)en_bf;
        #pragma unroll
        for (int r = 0; r < 32; r++) {
            int row = s_rowid[q4 * 32 + r];
            enreg[r] = enw[((size_t)b * TE + row) * (DE / 2) + e2];
        }
    }
    // private ctx slab: this (b,g)'s dead en_bf slice (64 steps x 512 f32)
    float* myctx = pctx + ((size_t)b * 1024 + g * RPB) * 256;

    __syncthreads();   // s_enc staged

    // pipelined dec fragment
    uint4 qd = *(const uint4*)(dec_bf + ((size_t)b * TD) * U + u);

    float inv_prev = 0.f;
    for (int s = 0; s < TD; s++) {
        // dfc = df * c (prescaled for the folded tanh argument)
        float dfc[8];
        unpack8(qd, dfc);
        #pragma unroll
        for (int j = 0; j < 8; j++) dfc[j] *= TANH_C;

        // ---- phase 1 (+fused phase 5 of step s-1) over own slots
        float local_esum = 0.f;
        for (int i = w; i < Sblk; i += 16) {
            float pold   = s_p[i];
            float covold = s_cov[i];
            float aprev  = pold * inv_prev;
            float cov    = covold + aprev;        // cov(s)
            if (s > 0 && lane == 0) {
                size_t rowo = ((size_t)b * TD + (s - 1)) * TE + s_rowid[i];
                alphas[rowo] = aprev;
                covl[rowo]   = fminf(covold, aprev);
            }
            uint4 q = *(const uint4*)(s_enc + (size_t)i * U + u);
            float e[8]; unpack8(q, e);
            float acc2 = 0.f;
            #pragma unroll
            for (int j = 0; j < 8; j++) {
                float arg = fmaf(cov, wcc[j], fmaf(e[j], TANH_C, dfc[j]));
                acc2 = fmaf(vv[j], RCPF(EXP2F(arg) + 1.0f), acc2);
            }
            // per-lane mu partial = vsum_l - 2*acc2_l (original cancellation)
            float part = fmaf(acc2, -2.0f, vsuml);
            part = wave_reduce_sum(part);         // = mu (wave-uniform)
            float pe = EXP2F(part * L2E);
            if (lane == 0) { s_p[i] = pe; s_cov[i] = cov; }
            local_esum += pe;
        }
        if (lane == 0) s_wsum[w] = local_esum;

        LBAR();   // B1: s_p/s_cov/s_wsum visible (LDS-only; no vmcnt drain)

        // ---- publish (sum_g | tag s+1): wave 0 lane 0
        unsigned long long* sl = stats + ((size_t)(s & 1) * B + b) * NB;
        if (w == 0) {
            float x = (lane < 16) ? s_wsum[lane] : 0.f;
            x += __shfl_xor(x, 8, 64);
            x += __shfl_xor(x, 4, 64);
            x += __shfl_xor(x, 2, 64);
            x += __shfl_xor(x, 1, 64);            // lane0: sum of 16
            if (lane == 0) {
                unsigned long long pv =
                    ((unsigned long long)__float_as_uint(x) << 32) |
                    (unsigned)(s + 1);
                st_agent64(&sl[g], pv);
            }
        }

        // ---- prefetch next dec fragment (hides under phase6 + poll)
        {
            int sn = (s + 1 < TD) ? s + 1 : s;
            qd = *(const uint4*)(dec_bf + (((size_t)b * TD + sn) * U + u));
        }

        // ---- phase 6: unnormalized ctx partial over own 32 slots -> s_q
        //      (s_p read as 8x float4: 4x fewer LDS instructions)
        {
            const float4* pb = (const float4*)&s_p[q4 * 32];
            float a0 = 0.f, a1 = 0.f;
            #pragma unroll
            for (int k = 0; k < 8; k++) {
                float4 pp = pb[k];
                a0 = fmaf(pp.x, bflo(enreg[4*k]),   a0);
                a1 = fmaf(pp.x, bfhi(enreg[4*k]),   a1);
                a0 = fmaf(pp.y, bflo(enreg[4*k+1]), a0);
                a1 = fmaf(pp.y, bfhi(enreg[4*k+1]), a1);
                a0 = fmaf(pp.z, bflo(enreg[4*k+2]), a0);
                a1 = fmaf(pp.z, bfhi(enreg[4*k+2]), a1);
                a0 = fmaf(pp.w, bflo(enreg[4*k+3]), a0);
                a1 = fmaf(pp.w, bfhi(enreg[4*k+3]), a1);
            }
            s_q[q4][2 * e2]     = a0;
            s_q[q4][2 * e2 + 1] = a1;
        }

        // ---- SINGLE-POLLER: wave 0 polls 8 tags -> inv -> s_inv
        if (w == 0) {
            unsigned long long pv = 0;
            for (;;) {
                if (lane < NB) pv = ld_agent64(&sl[lane]);
                unsigned long long okm =
                    __ballot(lane < NB ? ((unsigned)pv == (unsigned)(s + 1)) : 1);
                if (~okm == 0ull) break;
                __builtin_amdgcn_s_sleep(1);
            }
            float tg = (lane < NB) ? __uint_as_float((unsigned)(pv >> 32)) : 0.f;
            tg = wave_reduce_sum(tg);
            if (lane == 0) s_inv = RCPF(tg);
        }

        LBAR();   // B2: s_q + s_inv visible (LDS-only)

        inv_prev = s_inv;

        // ---- ctx(s) reduce + normalized plain store to private slab
        if (tid < 512) {
            float ts = s_q[0][tid] + s_q[1][tid] + s_q[2][tid] + s_q[3][tid];
            myctx[(size_t)s * 512 + tid] = ts * inv_prev;
        }
    }

    // ---- epilogue: flush alpha/covl for s = TD-1
    for (int i = w; i < Sblk; i += 16) {
        if (lane == 0) {
            float aprev = s_p[i] * inv_prev;
            size_t rowo = ((size_t)b * TD + (TD - 1)) * TE + s_rowid[i];
            alphas[rowo] = aprev;
            covl[rowo]   = fminf(s_cov[i], aprev);
        }
    }
    // myctx/alphas/covl drained at kernel boundary; k_ctx reads after.
}

// ---------------------------------------------------------------------------
// ctx final reduce: out ctx = sum over the 8 per-block partials.
// pctx[b][g] slab at float offset (b*1024+g*128)*256, laid out [s][e].
// Grid-strided to 256 blocks (dispatch-overhead cut).
__global__ __launch_bounds__(1024) void k_ctx(
        const float* __restrict__ pctx, float* __restrict__ out)
{
    for (int idx = blockIdx.x * 1024 + threadIdx.x; idx < 1048576;
         idx += 256 * 1024) {
        int b = idx >> 15, rem = idx & 32767;    // rem = s*512 + e
        const float* p = pctx + (size_t)b * 262144 + rem;
        float t = 0.f;
        #pragma unroll
        for (int g = 0; g < NB; g++) t += p[(size_t)g * 32768];
        int s = rem >> 9, e = rem & 511;
        out[((size_t)b * TD + s) * (DD + DE) + DD + e] = t;
    }
}

// ---------------------------------------------------------------------------
extern "C" void kernel_launch(void* const* d_in, const int* in_sizes, int n_in,
                              void* d_out, int out_size, void* d_ws, size_t ws_size,
                              hipStream_t stream) {
    const float* en_seq = (const float*)d_in[0];
    const float* de_seq = (const float*)d_in[1];
    const int*   mask   = (const int*)d_in[2];
    const float* W_h    = (const float*)d_in[3];
    const float* W_s    = (const float*)d_in[4];
    const float* w_c    = (const float*)d_in[5];
    const float* v      = (const float*)d_in[6];
    float* out = (float*)d_out;

    // workspace layout (~69 MiB). en_bf doubles as the per-block ctx-partial
    // slab during k_scan (each block's 128-KiB en slice is dead after the
    // batch-wide enreg staging, which completes before the first tag round).
    unsigned short* enc_bf = (unsigned short*)d_ws;        // B*TE*U  bf16 = 32 MiB
    unsigned short* en_bf  = enc_bf + (size_t)B * TE * U;  // B*TE*DE bf16 = 32 MiB
    unsigned short* dec_bf = en_bf  + (size_t)B * TE * DE; // B*TD*U  bf16 = 2 MiB
    unsigned short* Wh_t   = dec_bf + (size_t)B * TD * U;  // 512*512 bf16 = 0.5 MiB
    unsigned short* de_bf  = Wh_t   + (size_t)K * U;       // B*TD*DD bf16 = 2 MiB
    unsigned short* Ws_t   = de_bf  + (size_t)B * TD * DD; // 0.5 MiB
    unsigned long long* stats =
        (unsigned long long*)(Ws_t + (size_t)K * U);       // 512 u64
    float* pctx = (float*)en_bf;                           // alias

    k_prep<<<2048, 256, 0, stream>>>((const float4*)en_seq, (ushort4*)en_bf,
                                     (const float4*)de_seq, (ushort4*)de_bf,
                                     (float4*)out, W_h, Wh_t, W_s, Ws_t, stats);
    k_mfma<<<dim3(4, 272), 256, 0, stream>>>(en_bf, Wh_t, enc_bf,
                                             de_bf, Ws_t, dec_bf);

    void* args[] = { (void*)&enc_bf, (void*)&dec_bf, (void*)&en_bf,
                     (void*)&w_c, (void*)&v, (void*)&mask,
                     (void*)&stats, (void*)&pctx, (void*)&out };
    hipLaunchCooperativeKernel((const void*)k_scan, dim3(256), dim3(1024),
                               args, 0, stream);

    k_ctx<<<256, 1024, 0, stream>>>(pctx, out);
}

// Round 9
// 514.353 us; speedup vs baseline: 1.5049x; 1.0588x over previous
//
#include <hip/hip_runtime.h>
#include <float.h>

// Problem constants
#define B   32
#define TE  1024
#define TD  64
#define DE  512
#define DD  512
#define U   512
#define K   512   // == DE == DD
#define NB  8     // blocks per batch (256-block coop launch: proven geometry)
#define RPB 128   // t-rows per block (slice size for outputs/slab)

#if __has_builtin(__builtin_amdgcn_exp2f)
#define EXP2F __builtin_amdgcn_exp2f
#else
#define EXP2F exp2f
#endif
#if __has_builtin(__builtin_amdgcn_rcpf)
#define RCPF __builtin_amdgcn_rcpf
#else
#define RCPF(x) (1.0f / (x))
#endif

#define TANH_C 2.8853900817779268f   // 2*log2(e)
#define L2E    1.4426950408889634f

typedef __attribute__((ext_vector_type(8))) short bf16x8;  // 8 bf16 = 4 VGPRs
typedef __attribute__((ext_vector_type(4))) float f32x4;

// Blocked bf16 operand layout (MFMA-native, wave-coalesced fragment loads):
//   element (m,k) of an [M][512] panel lives at
//   ((m>>4)*64 + (k>>3))*128 + (m&15)*8 + (k&7)
// A wave's 16x32 fragment load (quad=k-chunk, l16=m) is then 1 KB contiguous.

__device__ __forceinline__ float wave_reduce_sum(float v) {
    #pragma unroll
    for (int o = 32; o; o >>= 1) v += __shfl_xor(v, o, 64);
    return v;
}

// f32 -> bf16 RNE
__device__ __forceinline__ unsigned short f2bf(float f) {
    unsigned u = __float_as_uint(f);
    unsigned r = (u + 0x7fffu + ((u >> 16) & 1u)) >> 16;
    return (unsigned short)r;
}
__device__ __forceinline__ float bflo(unsigned x) { return __uint_as_float(x << 16); }
__device__ __forceinline__ float bfhi(unsigned x) { return __uint_as_float(x & 0xffff0000u); }
__device__ __forceinline__ void unpack8(uint4 q, float* f) {
    f[0] = bflo(q.x); f[1] = bfhi(q.x); f[2] = bflo(q.y); f[3] = bfhi(q.y);
    f[4] = bflo(q.z); f[5] = bfhi(q.z); f[6] = bflo(q.w); f[7] = bfhi(q.w);
}

// relaxed agent-scope accessors (tag exchange only)
__device__ __forceinline__ unsigned long long ld_agent64(const unsigned long long* p) {
    return __hip_atomic_load(p, __ATOMIC_RELAXED, __HIP_MEMORY_SCOPE_AGENT);
}
__device__ __forceinline__ void st_agent64(unsigned long long* p, unsigned long long v) {
    __hip_atomic_store(p, v, __ATOMIC_RELAXED, __HIP_MEMORY_SCOPE_AGENT);
}

// LDS-only barrier: no vmcnt drain (loop has no intra-kernel vmem reader)
#define LBAR() do { \
    asm volatile("s_waitcnt lgkmcnt(0)" ::: "memory"); \
    __builtin_amdgcn_s_barrier(); \
    __builtin_amdgcn_sched_barrier(0); \
} while (0)

// ---------------------------------------------------------------------------
// Fused prep, grid-strided over 3329 virtual blocks:
//   [0,2048)    en_seq f32 -> en_bf  BLOCKED bf16 (16-row tiles via LDS)
//   [2048,2176) de_seq f32 -> de_bf  BLOCKED bf16
//   [2176,3200) de_seq passthrough -> out[:,:,0:DD]
//   [3200,3328) W transpose+cast -> Wh_t/Ws_t BLOCKED bf16
//   [3328]      stats init (512 u64)
// One 16640-B shared buffer serves both the 16x520 bf16 shuffle tile and the
// 64x65 f32 transpose tile (branch-exclusive; barrier at branch end).
__global__ __launch_bounds__(256) void k_prep(
        const float* __restrict__ en_seq, unsigned short* __restrict__ en_bf,
        const float* __restrict__ de_seq, unsigned short* __restrict__ de_bf,
        float4* __restrict__ outp,
        const float* __restrict__ W_h, unsigned short* __restrict__ Wh_t,
        const float* __restrict__ W_s, unsigned short* __restrict__ Ws_t,
        unsigned long long* __restrict__ stats)
{
    __shared__ __align__(16) unsigned char sbuf[16640];
    const int tid = threadIdx.x;
    for (int vb = blockIdx.x; vb < 3329; vb += 2048) {
        if (vb < 2176) {                 // blocked bf16 cast (en / de)
            const float* src; unsigned short* dst; int rb;
            if (vb < 2048) { src = en_seq; dst = en_bf; rb = vb; }
            else           { src = de_seq; dst = de_bf; rb = vb - 2048; }
            unsigned short* tbl = (unsigned short*)sbuf;   // [16][520] padded
            const float4* s4 = (const float4*)(src + (size_t)rb * 8192);
            #pragma unroll
            for (int i = 0; i < 8; i++) {                  // coalesced read
                int idx = tid + i * 256;                   // float4 index
                float4 f = s4[idx];
                ushort4 r; r.x = f2bf(f.x); r.y = f2bf(f.y);
                r.z = f2bf(f.z); r.w = f2bf(f.w);
                // (m = idx>>7, k = (idx&127)*4) -> LDS row-major padded
                *(ushort4*)&tbl[(idx >> 7) * 520 + (idx & 127) * 4] = r;
            }
            __syncthreads();
            uint4* d4 = (uint4*)(dst + (size_t)rb * 8192); // coalesced write
            #pragma unroll
            for (int i = 0; i < 4; i++) {
                int c = tid + i * 256;                     // 8-elem chunk id
                // dest chunk c = (kc*16 + m16); src LDS [m16][kc*8..+7]
                d4[c] = *(const uint4*)&tbl[(c & 15) * 520 + (c >> 4) * 8];
            }
            __syncthreads();
        } else if (vb < 3200) {          // de_seq passthrough -> out[:,:,0:DD]
            size_t i = (size_t)(vb - 2176) * 256 + tid;
            size_t r = i >> 7, c = i & 127;
            outp[r * 256 + c] = ((const float4*)de_seq)[i];
        } else if (vb < 3328) {          // W transpose+cast, BLOCKED dest
            int id = vb - 3200;
            const float* W = (id < 64) ? W_h : W_s;
            unsigned short* Wt = (id < 64) ? Wh_t : Ws_t;
            int bid = id & 63;
            const int bx = bid & 7, by = bid >> 3;
            const int lx = tid & 63, ly = tid >> 6;
            float* t = (float*)sbuf;     // [64][65]
            #pragma unroll
            for (int i = 0; i < 64; i += 4)
                t[(ly + i) * 65 + lx] =
                    W[(size_t)(by * 64 + ly + i) * 512 + bx * 64 + lx];
            __syncthreads();
            #pragma unroll
            for (int i = 0; i < 64; i += 4) {
                int n = bx * 64 + ly + i, k = by * 64 + lx;
                Wt[((size_t)(n >> 4) * 64 + (k >> 3)) * 128
                   + (n & 15) * 8 + (k & 7)] = f2bf(t[lx * 65 + ly + i]);
            }
            __syncthreads();
        } else {                         // stats init (512 u64)
            stats[tid] = 0ull;
            stats[tid + 256] = 0ull;
        }
    }
}

// ---------------------------------------------------------------------------
// Unified MFMA GEMM: C_bf16[M,512] = A_blk[M,512] @ Wt_blk[512,512]^T.
// grid (4, 272): y<256 -> enc (M=32768), y>=256 -> dec (M=2048).
// Operands in blocked layout -> every fragment load is a wave-contiguous
// 1 KB read (was 16B x 16 scattered rows). C output stays row-major.
__global__ __launch_bounds__(256) void k_mfma(
        const unsigned short* __restrict__ Ae, const unsigned short* __restrict__ Be,
        unsigned short* __restrict__ Ce,
        const unsigned short* __restrict__ Ad, const unsigned short* __restrict__ Bd,
        unsigned short* __restrict__ Cd)
{
    const int tid = threadIdx.x;
    const int w = tid >> 6, lane = tid & 63;
    const int quad = lane >> 4, l16 = lane & 15;
    const short* A; const short* Bt; unsigned short* C; int mb;
    if (blockIdx.y < 256) {
        A = (const short*)Ae; Bt = (const short*)Be; C = Ce; mb = blockIdx.y * 128;
    } else {
        A = (const short*)Ad; Bt = (const short*)Bd; C = Cd; mb = (blockIdx.y - 256) * 128;
    }
    const int m0 = mb + (w >> 1) * 64;
    const int n0 = blockIdx.x * 128 + (w & 1) * 64;

    // blocked bases (+ per-lane m/n offset)
    const short* Ab = A  + (size_t)(m0 >> 4) * 64 * 128 + l16 * 8;
    const short* Bb = Bt + (size_t)(n0 >> 4) * 64 * 128 + l16 * 8;

    f32x4 acc[4][4] = {};
    for (int ks = 0; ks < K; ks += 32) {
        const int kc = (ks >> 3) + quad;      // this lane's k-chunk
        bf16x8 af[4], bg[4];
        #pragma unroll
        for (int i = 0; i < 4; i++)
            af[i] = *(const bf16x8*)(Ab + ((size_t)i * 64 + kc) * 128);
        #pragma unroll
        for (int j = 0; j < 4; j++)
            bg[j] = *(const bf16x8*)(Bb + ((size_t)j * 64 + kc) * 128);
        #pragma unroll
        for (int i = 0; i < 4; i++)
            #pragma unroll
            for (int j = 0; j < 4; j++)
                acc[i][j] = __builtin_amdgcn_mfma_f32_16x16x32_bf16(
                    af[i], bg[j], acc[i][j], 0, 0, 0);
    }
    #pragma unroll
    for (int i = 0; i < 4; i++)
        #pragma unroll
        for (int j = 0; j < 4; j++)
            #pragma unroll
            for (int r = 0; r < 4; r++) {
                int m = m0 + i * 16 + quad * 4 + r;
                int n = n0 + j * 16 + l16;
                C[(size_t)m * U + n] = f2bf(acc[i][j][r]);
            }
}

// ---------------------------------------------------------------------------
// Persistent scan v6 (byte-identical loop to the proven 345us version):
// 256 blocks x 1024 threads, cooperative. Single-poller + balanced dealing +
// fused phase5 + tanh strength-reduction + LDS-only barriers. Only the
// one-time enreg hoist changed: en_bf is now in blocked layout.
__global__ __launch_bounds__(1024, 4) void k_scan(
        const unsigned short* __restrict__ enc_bf,
        const unsigned short* __restrict__ dec_bf,
        const unsigned short* en_bf,     // aliases pctx!
        const float* __restrict__ w_c,
        const float* __restrict__ v,
        const int* __restrict__ mask,
        unsigned long long* __restrict__ stats,  // [2][B][NB]
        float* pctx,                     // aliases en_bf! per-(b,g) slabs
        float* __restrict__ out)
{
    const int blk = blockIdx.x;
    const int b = blk & 31, g = blk >> 5;    // batch's 8 blocks share an XCD
    const int tid = threadIdx.x;
    const int w = tid >> 6, lane = tid & 63;
    const int u = lane * 8;

    __shared__ __align__(16) unsigned short s_enc[RPB * U];  // 128 KiB (by slot)
    __shared__ __align__(16) float s_p[RPB];  // unnormalized exp2(mu*L2E)/slot
    __shared__ float  s_cov[RPB];     // coverage per slot
    __shared__ short  s_rowid[RPB];   // slot -> batch row
    __shared__ unsigned long long s_bal[16];
    __shared__ float  s_wsum[16];
    __shared__ float  s_q[4][512];    // quarter ctx partials, 8 KiB
    __shared__ float  s_inv;

    const int* maskb = mask + b * TE;
    float* alphas = out + (size_t)B * TD * (DD + DE);
    float* covl   = alphas + (size_t)B * TD * TE;

    // lane-resident fragments: wcc = w_c*c (prescaled), vv, vsum (per-lane)
    float wcc[8], vv[8], vsuml;
    {
        float4 a0 = *(const float4*)&w_c[u];
        float4 a1 = *(const float4*)&w_c[u + 4];
        wcc[0]=a0.x*TANH_C; wcc[1]=a0.y*TANH_C; wcc[2]=a0.z*TANH_C; wcc[3]=a0.w*TANH_C;
        wcc[4]=a1.x*TANH_C; wcc[5]=a1.y*TANH_C; wcc[6]=a1.z*TANH_C; wcc[7]=a1.w*TANH_C;
        float4 b0 = *(const float4*)&v[u];
        float4 b1 = *(const float4*)&v[u + 4];
        vv[0]=b0.x; vv[1]=b0.y; vv[2]=b0.z; vv[3]=b0.w;
        vv[4]=b1.x; vv[5]=b1.y; vv[6]=b1.z; vv[7]=b1.w;
        vsuml = ((vv[0]+vv[1])+(vv[2]+vv[3])) + ((vv[4]+vv[5])+(vv[6]+vv[7]));
    }

    // ---- global active-row compaction (identical in all 8 blocks of b)
    int act = (maskb[tid] != 0);
    {
        unsigned long long bal = __ballot(act);
        if (lane == 0) s_bal[w] = bal;
        if (tid < RPB) { s_p[tid] = 0.f; s_cov[tid] = 0.f; s_rowid[tid] = 0; }
        __syncthreads();
    }
    int nact = 0, pre = 0;
    {
        #pragma unroll
        for (int ww = 0; ww < 16; ww++) {
            int c = __popcll(s_bal[ww]);
            if (ww < w) pre += c;
            nact += c;
        }
        pre += __popcll(s_bal[w] & ((1ull << lane) - 1));
        if (act && (pre & 7) == g) s_rowid[pre >> 3] = (short)tid;
    }
    const int Sblk = (nact + 7 - g) >> 3;    // assigned slots (<=128)

    // ---- zero alpha/covl for inactive rows of OWN slice, all steps (once)
    for (int t = tid; t < RPB * TD; t += 1024) {
        int rl = t & 127, s = t >> 7;
        if (maskb[g * RPB + rl] == 0) {
            size_t rowo = ((size_t)b * TD + s) * TE + g * RPB + rl;
            alphas[rowo] = 0.f;
            covl[rowo]   = 0.f;
        }
    }
    __syncthreads();   // s_rowid ready

    // ---- stage assigned rows' enc into LDS (slot-major), gather by rowid
    {
        const int slot = tid >> 3, part = tid & 7;   // 128 slots x 8 parts
        const uint4* src = (const uint4*)
            (enc_bf + ((size_t)b * TE + s_rowid[slot]) * U);
        uint4* dst = (uint4*)(s_enc + (size_t)slot * U);
        #pragma unroll
        for (int j = 0; j < 8; j++) dst[part + j * 8] = src[part + j * 8];
    }
    // ---- hoist assigned rows' en words (phase6 operands), by rowid
    //      en_bf is BLOCKED: word(rg,e2) = ((rg>>4)*64+(e2>>2))*64+(rg&15)*4+(e2&3)
    const int e2 = tid & 255, q4 = tid >> 8;   // 256 e-pairs x 4 quarters
    unsigned enreg[32];
    {
        const unsigned* enw = (const unsigned*)en_bf;
        #pragma unroll
        for (int r = 0; r < 32; r++) {
            int rg = b * TE + s_rowid[q4 * 32 + r];
            enreg[r] = enw[((size_t)(rg >> 4) * 64 + (e2 >> 2)) * 64
                           + (rg & 15) * 4 + (e2 & 3)];
        }
    }
    // private ctx slab: this (b,g)'s dead en_bf slice (64 steps x 512 f32)
    float* myctx = pctx + ((size_t)b * 1024 + g * RPB) * 256;

    __syncthreads();   // s_enc staged

    // pipelined dec fragment
    uint4 qd = *(const uint4*)(dec_bf + ((size_t)b * TD) * U + u);

    float inv_prev = 0.f;
    for (int s = 0; s < TD; s++) {
        // dfc = df * c (prescaled for the folded tanh argument)
        float dfc[8];
        unpack8(qd, dfc);
        #pragma unroll
        for (int j = 0; j < 8; j++) dfc[j] *= TANH_C;

        // ---- phase 1 (+fused phase 5 of step s-1) over own slots
        float local_esum = 0.f;
        for (int i = w; i < Sblk; i += 16) {
            float pold   = s_p[i];
            float covold = s_cov[i];
            float aprev  = pold * inv_prev;
            float cov    = covold + aprev;        // cov(s)
            if (s > 0 && lane == 0) {
                size_t rowo = ((size_t)b * TD + (s - 1)) * TE + s_rowid[i];
                alphas[rowo] = aprev;
                covl[rowo]   = fminf(covold, aprev);
            }
            uint4 q = *(const uint4*)(s_enc + (size_t)i * U + u);
            float e[8]; unpack8(q, e);
            float acc2 = 0.f;
            #pragma unroll
            for (int j = 0; j < 8; j++) {
                float arg = fmaf(cov, wcc[j], fmaf(e[j], TANH_C, dfc[j]));
                acc2 = fmaf(vv[j], RCPF(EXP2F(arg) + 1.0f), acc2);
            }
            // per-lane mu partial = vsum_l - 2*acc2_l (original cancellation)
            float part = fmaf(acc2, -2.0f, vsuml);
            part = wave_reduce_sum(part);         // = mu (wave-uniform)
            float pe = EXP2F(part * L2E);
            if (lane == 0) { s_p[i] = pe; s_cov[i] = cov; }
            local_esum += pe;
        }
        if (lane == 0) s_wsum[w] = local_esum;

        LBAR();   // B1: s_p/s_cov/s_wsum visible (LDS-only; no vmcnt drain)

        // ---- publish (sum_g | tag s+1): wave 0 lane 0
        unsigned long long* sl = stats + ((size_t)(s & 1) * B + b) * NB;
        if (w == 0) {
            float x = (lane < 16) ? s_wsum[lane] : 0.f;
            x += __shfl_xor(x, 8, 64);
            x += __shfl_xor(x, 4, 64);
            x += __shfl_xor(x, 2, 64);
            x += __shfl_xor(x, 1, 64);            // lane0: sum of 16
            if (lane == 0) {
                unsigned long long pv =
                    ((unsigned long long)__float_as_uint(x) << 32) |
                    (unsigned)(s + 1);
                st_agent64(&sl[g], pv);
            }
        }

        // ---- prefetch next dec fragment (hides under phase6 + poll)
        {
            int sn = (s + 1 < TD) ? s + 1 : s;
            qd = *(const uint4*)(dec_bf + (((size_t)b * TD + sn) * U + u));
        }

        // ---- phase 6: unnormalized ctx partial over own 32 slots -> s_q
        //      (s_p read as 8x float4: 4x fewer LDS instructions)
        {
            const float4* pb = (const float4*)&s_p[q4 * 32];
            float a0 = 0.f, a1 = 0.f;
            #pragma unroll
            for (int k = 0; k < 8; k++) {
                float4 pp = pb[k];
                a0 = fmaf(pp.x, bflo(enreg[4*k]),   a0);
                a1 = fmaf(pp.x, bfhi(enreg[4*k]),   a1);
                a0 = fmaf(pp.y, bflo(enreg[4*k+1]), a0);
                a1 = fmaf(pp.y, bfhi(enreg[4*k+1]), a1);
                a0 = fmaf(pp.z, bflo(enreg[4*k+2]), a0);
                a1 = fmaf(pp.z, bfhi(enreg[4*k+2]), a1);
                a0 = fmaf(pp.w, bflo(enreg[4*k+3]), a0);
                a1 = fmaf(pp.w, bfhi(enreg[4*k+3]), a1);
            }
            s_q[q4][2 * e2]     = a0;
            s_q[q4][2 * e2 + 1] = a1;
        }

        // ---- SINGLE-POLLER: wave 0 polls 8 tags -> inv -> s_inv
        if (w == 0) {
            unsigned long long pv = 0;
            for (;;) {
                if (lane < NB) pv = ld_agent64(&sl[lane]);
                unsigned long long okm =
                    __ballot(lane < NB ? ((unsigned)pv == (unsigned)(s + 1)) : 1);
                if (~okm == 0ull) break;
                __builtin_amdgcn_s_sleep(1);
            }
            float tg = (lane < NB) ? __uint_as_float((unsigned)(pv >> 32)) : 0.f;
            tg = wave_reduce_sum(tg);
            if (lane == 0) s_inv = RCPF(tg);
        }

        LBAR();   // B2: s_q + s_inv visible (LDS-only)

        inv_prev = s_inv;

        // ---- ctx(s) reduce + normalized plain store to private slab
        if (tid < 512) {
            float ts = s_q[0][tid] + s_q[1][tid] + s_q[2][tid] + s_q[3][tid];
            myctx[(size_t)s * 512 + tid] = ts * inv_prev;
        }
    }

    // ---- epilogue: flush alpha/covl for s = TD-1
    for (int i = w; i < Sblk; i += 16) {
        if (lane == 0) {
            float aprev = s_p[i] * inv_prev;
            size_t rowo = ((size_t)b * TD + (TD - 1)) * TE + s_rowid[i];
            alphas[rowo] = aprev;
            covl[rowo]   = fminf(s_cov[i], aprev);
        }
    }
    // myctx/alphas/covl drained at kernel boundary; k_ctx reads after.
}

// ---------------------------------------------------------------------------
// ctx final reduce: out ctx = sum over the 8 per-block partials.
// pctx[b][g] slab at float offset (b*1024+g*128)*256, laid out [s][e].
// Grid-strided to 256 blocks.
__global__ __launch_bounds__(1024) void k_ctx(
        const float* __restrict__ pctx, float* __restrict__ out)
{
    for (int idx = blockIdx.x * 1024 + threadIdx.x; idx < 1048576;
         idx += 256 * 1024) {
        int b = idx >> 15, rem = idx & 32767;    // rem = s*512 + e
        const float* p = pctx + (size_t)b * 262144 + rem;
        float t = 0.f;
        #pragma unroll
        for (int g = 0; g < NB; g++) t += p[(size_t)g * 32768];
        int s = rem >> 9, e = rem & 511;
        out[((size_t)b * TD + s) * (DD + DE) + DD + e] = t;
    }
}

// ---------------------------------------------------------------------------
extern "C" void kernel_launch(void* const* d_in, const int* in_sizes, int n_in,
                              void* d_out, int out_size, void* d_ws, size_t ws_size,
                              hipStream_t stream) {
    const float* en_seq = (const float*)d_in[0];
    const float* de_seq = (const float*)d_in[1];
    const int*   mask   = (const int*)d_in[2];
    const float* W_h    = (const float*)d_in[3];
    const float* W_s    = (const float*)d_in[4];
    const float* w_c    = (const float*)d_in[5];
    const float* v      = (const float*)d_in[6];
    float* out = (float*)d_out;

    // workspace layout (~69 MiB, unchanged). en_bf doubles as the per-block
    // ctx-partial slab during k_scan (dead after the enreg hoist; per-batch
    // byte regions identical under the blocked layout).
    unsigned short* enc_bf = (unsigned short*)d_ws;        // B*TE*U  bf16 = 32 MiB
    unsigned short* en_bf  = enc_bf + (size_t)B * TE * U;  // B*TE*DE bf16 = 32 MiB (blocked)
    unsigned short* dec_bf = en_bf  + (size_t)B * TE * DE; // B*TD*U  bf16 = 2 MiB
    unsigned short* Wh_t   = dec_bf + (size_t)B * TD * U;  // 512*512 bf16 = 0.5 MiB (blocked)
    unsigned short* de_bf  = Wh_t   + (size_t)K * U;       // B*TD*DD bf16 = 2 MiB (blocked)
    unsigned short* Ws_t   = de_bf  + (size_t)B * TD * DD; // 0.5 MiB (blocked)
    unsigned long long* stats =
        (unsigned long long*)(Ws_t + (size_t)K * U);       // 512 u64
    float* pctx = (float*)en_bf;                           // alias

    k_prep<<<2048, 256, 0, stream>>>(en_seq, en_bf, de_seq, de_bf,
                                     (float4*)out, W_h, Wh_t, W_s, Ws_t, stats);
    k_mfma<<<dim3(4, 272), 256, 0, stream>>>(en_bf, Wh_t, enc_bf,
                                             de_bf, Ws_t, dec_bf);

    void* args[] = { (void*)&enc_bf, (void*)&dec_bf, (void*)&en_bf,
                     (void*)&w_c, (void*)&v, (void*)&mask,
                     (void*)&stats, (void*)&pctx, (void*)&out };
    hipLaunchCooperativeKernel((const void*)k_scan, dim3(256), dim3(1024),
                               args, 0, stream);

    k_ctx<<<256, 1024, 0, stream>>>(pctx, out);
}